// Round 13
// baseline (527.640 us; speedup 1.0000x reference)
//
#include <hip/hip_runtime.h>
#include <hip/hip_bf16.h>

// Attention_89335319756981 — MI355X bf16-MFMA implementation, round 13.
// B=8, N=2880 (hw=576 + T=4 frames of 576), C=768, H=12, hd=64, TOPK=32.
//
// Round-13 changes (base = round 10; r12's pure-VALU count reverted):
//  - 4-row batched ballot search (10-bit keys, 10 rounds): 40 independent
//    ballots/round overlap 4 SALU chains.
//  - writeback: per-row immediate stores, dsum butterflies batched 4-wide
//    (depth 6 shfl total instead of 24).
//  - opart partials in bf16 (halves partial write+read traffic).

using s16x8 = __attribute__((ext_vector_type(8))) short;
using f32x4 = __attribute__((ext_vector_type(4))) float;
typedef unsigned short u16;
typedef unsigned int u32;

#define MFMA_B16(A,B,C) __builtin_amdgcn_mfma_f32_16x16x32_bf16(A,B,C,0,0,0)

__device__ __forceinline__ u16 f2bf(float f) {
  unsigned u = __float_as_uint(f);
  u += 0x7FFFu + ((u >> 16) & 1u);          // RNE, no NaN inputs here
  return (u16)(u >> 16);
}
__device__ __forceinline__ float bf2f(u16 h) {
  return __uint_as_float(((unsigned)h) << 16);
}
__device__ __forceinline__ int lanes_below(unsigned long long m) {
  return __builtin_amdgcn_mbcnt_hi((unsigned)(m >> 32),
         __builtin_amdgcn_mbcnt_lo((unsigned)m, 0));
}
__device__ __forceinline__ void stage16(const u16* __restrict__ g, u16* l) {
  __builtin_amdgcn_global_load_lds(
      (const __attribute__((address_space(1))) unsigned int*)g,
      (__attribute__((address_space(3))) unsigned int*)l, 16, 0, 0);
}
// sum of the two bf16 halves of a packed dword (zeros contribute 0)
__device__ __forceinline__ float sumpair(u32 d) {
  return __uint_as_float(d << 16) + __uint_as_float(d & 0xFFFF0000u);
}

// ---------------- f32 -> bf16 convert (4 elems/thread) ----------------
__global__ __launch_bounds__(256) void cvt_kernel(const float* __restrict__ src,
                                                  u16* __restrict__ dst, int n4) {
  int i = blockIdx.x * blockDim.x + threadIdx.x;
  if (i >= n4) return;
  float4 v = ((const float4*)src)[i];
  unsigned lo = (unsigned)f2bf(v.x) | ((unsigned)f2bf(v.y) << 16);
  unsigned hi = (unsigned)f2bf(v.z) | ((unsigned)f2bf(v.w) << 16);
  uint2 o; o.x = lo; o.y = hi;
  ((uint2*)dst)[i] = o;
}

// ---------------- passthrough copy: out[:,576:,:] = x[:,576:,:] ----------------
__global__ __launch_bounds__(256) void copy_tail_kernel(const float* __restrict__ x,
                                                        float* __restrict__ out) {
  int i = blockIdx.x * blockDim.x + threadIdx.x;   // float4 units
  int b = i / 442368;                              // 2304*768/4 per batch
  int off = i - b * 442368;
  size_t e = (size_t)b * 552960 + 110592 + off;    // (b*2880+576)*768/4 + off
  ((float4*)out)[e] = ((const float4*)x)[e];
}

// ---------------- NT GEMM, 128x128 tile, BK=64, global_load_lds ----------------
template<int MODE>
__global__ __launch_bounds__(256) void gemm_nt(
    const u16* __restrict__ A, const u16* __restrict__ Bw,
    const float* __restrict__ bias,
    u16* __restrict__ qbuf, u16* __restrict__ kbuf,
    u16* __restrict__ vtb, float* __restrict__ fout)
{
  __shared__ __align__(16) u16 smem[128 * 128];   // 32KB: sA|sB, reused for vT
  u16* sA = smem;
  u16* sB = smem + 128 * 64;
  const int n0 = blockIdx.x * 128;
  const int m0 = blockIdx.y * 128;
  if (MODE == 0 && n0 < 768) {
    const int s = m0 % 2880;
    if (s >= 576 && s + 128 <= 2880) return;
  }
  const int tid = threadIdx.x;
  const int w = tid >> 6, lane = tid & 63;
  const int l15 = lane & 15, rg = lane >> 4;
  const int ko = rg * 8;
  const int mq = (w >> 1) * 64, nq = (w & 1) * 64;
  const int trow = tid >> 3, tcol = (tid & 7) * 8;

  f32x4 z = {0.f, 0.f, 0.f, 0.f};
  f32x4 acc[4][4];
  #pragma unroll
  for (int i = 0; i < 4; ++i)
    #pragma unroll
    for (int j = 0; j < 4; ++j) acc[i][j] = z;

  for (int k0 = 0; k0 < 768; k0 += 64) {
    __syncthreads();
    #pragma unroll
    for (int i = 0; i < 4; ++i) {
      stage16(&A[(size_t)(m0 + trow + i * 32) * 768 + k0 + tcol],
              &sA[(trow + i * 32) * 64 + tcol]);
      stage16(&Bw[(size_t)(n0 + trow + i * 32) * 768 + k0 + tcol],
              &sB[(trow + i * 32) * 64 + tcol]);
    }
    __syncthreads();
    #pragma unroll
    for (int kk = 0; kk < 2; ++kk) {
      const int ko2 = kk * 32 + ko;
      s16x8 af[4], bf[4];
      #pragma unroll
      for (int i = 0; i < 4; ++i) {
        af[i] = *(const s16x8*)&sA[(mq + i * 16 + l15) * 64 + ko2];
        bf[i] = *(const s16x8*)&sB[(nq + i * 16 + l15) * 64 + ko2];
      }
      #pragma unroll
      for (int mi = 0; mi < 4; ++mi)
        #pragma unroll
        for (int ni = 0; ni < 4; ++ni)
          acc[mi][ni] = MFMA_B16(af[mi], bf[ni], acc[mi][ni]);
    }
  }

  if (MODE == 0) {
    const int which = n0 / 768;
    const int nb = n0 % 768;
    if (which == 2) {
      __syncthreads();
      #pragma unroll
      for (int mi = 0; mi < 4; ++mi)
        #pragma unroll
        for (int ni = 0; ni < 4; ++ni)
          #pragma unroll
          for (int r = 0; r < 4; ++r)
            smem[(mq + mi * 16 + rg * 4 + r) * 128 + nq + ni * 16 + l15] =
                f2bf(acc[mi][ni][r]);
      __syncthreads();
      const int c = tid & 127, kh = tid >> 7;
      const int gm0 = m0 + kh * 64;
      const int bb = gm0 / 2880, rr0 = gm0 - bb * 2880;
      const int ng = nb + c;
      const int hh = ng >> 6, dd = ng & 63;
      u16* dst = vtb + ((size_t)((bb * 12 + hh) * 64 + dd)) * 2880 + rr0;
      #pragma unroll
      for (int seg = 0; seg < 4; ++seg) {
        u16 tmp[16];
        #pragma unroll
        for (int i = 0; i < 16; ++i)
          tmp[i] = smem[(kh * 64 + seg * 16 + i) * 128 + c];
        *(int4*)&dst[seg * 16]     = *(const int4*)&tmp[0];
        *(int4*)&dst[seg * 16 + 8] = *(const int4*)&tmp[8];
      }
    } else {
      #pragma unroll
      for (int mi = 0; mi < 4; ++mi)
        #pragma unroll
        for (int ni = 0; ni < 4; ++ni)
          #pragma unroll
          for (int r = 0; r < 4; ++r) {
            const int gm = m0 + mq + mi * 16 + rg * 4 + r;
            const int b  = gm / 2880;
            const int rr = gm - b * 2880;
            const int ng = nb + nq + ni * 16 + l15;
            const int h  = ng >> 6, d = ng & 63;
            const float cc = acc[mi][ni][r];
            if (which == 0) {
              if (rr < 576)
                qbuf[((size_t)(b * 12 + h) * 576 + rr) * 64 + d] = f2bf(cc * 0.125f);
            } else {
              kbuf[((size_t)(b * 12 + h) * 2880 + rr) * 64 + d] = f2bf(cc);
            }
          }
    }
  } else {
    #pragma unroll
    for (int mi = 0; mi < 4; ++mi)
      #pragma unroll
      for (int ni = 0; ni < 4; ++ni)
        #pragma unroll
        for (int r = 0; r < 4; ++r) {
          const int gm = m0 + mq + mi * 16 + rg * 4 + r;
          const int gn = n0 + nq + ni * 16 + l15;
          const int b = gm / 576;
          const int q = gm - b * 576;
          fout[((size_t)b * 2880 + q) * 768 + gn] = acc[mi][ni][r] + bias[gn];
        }
  }
}

// ---------------- fused attention, round 13: one key-chunk per block ----------------
// block = (b, h, 16 q-rows, chunk c), 256 threads (4 waves), ~20.7KB LDS,
// 7 blocks/CU. Top-32: 10-round ballot binary search on 10-bit compact keys,
// 4-row batched; writeback per-row, dsum butterflies batched 4-wide.
// Partials: O_c bf16, denom_c f32 -> ws.
__global__ __launch_bounds__(256, 7) void attn_kernel(
    const u16* __restrict__ qbuf, const u16* __restrict__ kbuf,
    const u16* __restrict__ vtb,
    u16* __restrict__ opart, float* __restrict__ dpart)
{
  constexpr int PST = 648;                       // u16 stride: 1296B
  constexpr int BIAS = 0x3E80;                   // exp-bf16 code of ~0.25
  __shared__ __align__(16) u16 s_p[16 * PST];    // 20.7 KB exp(scores) / P

  const int bid = blockIdx.x;
  const int L = (bid & 7) * 2160 + (bid >> 3);   // 17280 = 8 XCD * 2160
  const int b   = L / 2160;
  const int rm  = L % 2160;
  const int c   = rm / 432;                      // chunk 0..4
  const int h   = (rm / 36) % 12;
  const int qt  = rm % 36;
  const int bh = b * 12 + h;
  const int q0 = qt * 16;
  const int bq = bh * 36 + qt;
  const int tid = threadIdx.x, w = tid >> 6, lane = tid & 63;
  const int l15 = lane & 15, rg = lane >> 4;
  const int ko = rg * 8;

  // zero the pad region u16[576..640) of each row (read by vector key loads)
  #pragma unroll
  for (int i = 0; i < 2; ++i) {
    const int idx = tid + 256 * i;               // 0..511
    const int row = idx >> 5, dw = idx & 31;
    *(u32*)&s_p[row * PST + 576 + dw * 2] = 0u;
  }

  // Q A-fragments for the block's 16 rows (2 K-halves)
  const u16* qp = qbuf + ((size_t)bh * 576 + q0) * 64;
  s16x8 aQ[2];
  aQ[0] = *(const s16x8*)&qp[l15 * 64 + ko];
  aQ[1] = *(const s16x8*)&qp[l15 * 64 + 32 + ko];

  const u16* kp = kbuf + (size_t)bh * 2880 * 64;
  const u16* vt = vtb + ((size_t)bh * 64 + w * 16 + l15) * 2880;
  f32x4 zz = {0.f, 0.f, 0.f, 0.f};
  f32x4 accO = zz;

  // ---- scores (stored as exp, truncated): wave w keys [w*144, w*144+144) ----
  #pragma unroll 3
  for (int t = 0; t < 9; ++t) {
    const int wk = w * 144 + t * 16;
    const u16* kr = kp + (size_t)(c * 576 + wk + l15) * 64 + ko;
    s16x8 kf0 = *(const s16x8*)&kr[0];
    s16x8 kf1 = *(const s16x8*)&kr[32];
    f32x4 a0 = zz;
    a0 = MFMA_B16(aQ[0], kf0, a0);
    a0 = MFMA_B16(aQ[1], kf1, a0);
    #pragma unroll
    for (int r = 0; r < 4; ++r)
      s_p[(rg * 4 + r) * PST + wk + l15] =
          (u16)(__float_as_uint(__expf(a0[r])) >> 16);   // truncate
  }
  __syncthreads();

  if (c == 0) {
    // ---- denom over qa: wave w owns rows w*4..w*4+3 (vectorized reads) ----
    #pragma unroll
    for (int ri = 0; ri < 4; ++ri) {
      const int q = w * 4 + ri;
      const u32* rp = (const u32*)&s_p[q * PST];
      uint4 dv = *(const uint4*)&rp[lane * 4];   // u16 idx 8L..8L+7
      u32 tl = rp[256 + lane];                   // u16 idx 512+2L..513+2L (pad=0)
      float s = sumpair(dv.x) + sumpair(dv.y) + sumpair(dv.z) + sumpair(dv.w)
              + sumpair(tl);
      #pragma unroll
      for (int off = 1; off < 64; off <<= 1) s += __shfl_xor(s, off);
      if (lane == 0) dpart[(size_t)(bq * 5 + c) * 16 + q] = s;
    }
    // no second barrier: PV and denom both only READ s_p
  } else {
    // ---- top-32: 4-row batched, 10-bit compact keys, ballot counting ----
    u32 key[4][10];
    #pragma unroll
    for (int ri = 0; ri < 4; ++ri) {
      const u32* rp = (const u32*)&s_p[(w * 4 + ri) * PST];
      uint4 dv = *(const uint4*)&rp[lane * 4];
      u32 tl = rp[256 + lane];
      key[ri][0]=dv.x&0xFFFF; key[ri][1]=dv.x>>16;
      key[ri][2]=dv.y&0xFFFF; key[ri][3]=dv.y>>16;
      key[ri][4]=dv.z&0xFFFF; key[ri][5]=dv.z>>16;
      key[ri][6]=dv.w&0xFFFF; key[ri][7]=dv.w>>16;
      key[ri][8]=tl&0xFFFF;   key[ri][9]=tl>>16;
    }
    #pragma unroll
    for (int ri = 0; ri < 4; ++ri)
      #pragma unroll
      for (int j = 0; j < 10; ++j) {             // compact: clamp(k-BIAS, 0, 1023)
        const int t2 = (int)key[ri][j] - BIAS;
        key[ri][j] = (u32)(t2 < 0 ? 0 : (t2 > 1023 ? 1023 : t2));
      }
    u32 pf[4] = {0u, 0u, 0u, 0u};
    #pragma unroll
    for (int bit = 9; bit >= 0; --bit) {
      int cnt[4];
      #pragma unroll
      for (int ri = 0; ri < 4; ++ri) {
        const u32 cand = pf[ri] | (1u << bit);
        int cn = 0;
        #pragma unroll
        for (int j = 0; j < 10; ++j)
          cn += __popcll(__ballot(key[ri][j] >= cand));
        cnt[ri] = cn;
      }
      #pragma unroll
      for (int ri = 0; ri < 4; ++ri)
        if (cnt[ri] >= 32) pf[ri] |= (1u << bit);
    }
    // ---- writeback per row (immediate stores); dsum butterflies batched ----
    float ds4[4];
    #pragma unroll
    for (int ri = 0; ri < 4; ++ri) {
      const u32 pfx = pf[ri];
      int cnt_gt = 0;
      #pragma unroll
      for (int j = 0; j < 10; ++j)
        cnt_gt += __popcll(__ballot(key[ri][j] > pfx));
      const int rem = 32 - cnt_gt;               // tie slots (scan order)
      int run_eq = 0;
      u32 wd[5];
      float dsum = 0.f;
      #pragma unroll
      for (int j2 = 0; j2 < 5; ++j2) {
        u32 packed = 0;
        #pragma unroll
        for (int h2 = 0; h2 < 2; ++h2) {
          const int j = j2 * 2 + h2;
          const u32 kj = key[ri][j];
          unsigned long long eq = __ballot(kj == pfx);
          const bool sel = (kj > pfx) ||
              (kj == pfx && run_eq + lanes_below(eq) < rem);
          run_eq += __popcll(eq);
          const u32 w16 = sel ? (kj + (u32)BIAS) : 0u;
          packed |= w16 << (16 * h2);
        }
        wd[j2] = packed;
        dsum += sumpair(packed);
      }
      u32* rp = (u32*)&s_p[(w * 4 + ri) * PST];
      *(uint4*)&rp[lane * 4] = *(const uint4*)&wd[0];
      rp[256 + lane] = wd[4];
      ds4[ri] = dsum;
    }
    #pragma unroll
    for (int off = 1; off < 64; off <<= 1) {
      #pragma unroll
      for (int ri = 0; ri < 4; ++ri)
        ds4[ri] += __shfl_xor(ds4[ri], off);
    }
    if (lane == 0) {
      #pragma unroll
      for (int ri = 0; ri < 4; ++ri)
        dpart[(size_t)(bq * 5 + c) * 16 + w * 4 + ri] = ds4[ri];
    }
    __syncthreads();   // P writeback visible before PV reads all rows
  }

  // ---- dense PV over this chunk: wave w owns output cols d = w*16..+15 ----
  #pragma unroll 3
  for (int k0 = 0; k0 < 576; k0 += 32) {
    s16x8 vf = *(const s16x8*)&vt[(size_t)c * 576 + k0 + ko];
    s16x8 pa = *(const s16x8*)&s_p[l15 * PST + k0 + ko];
    accO = MFMA_B16(pa, vf, accO);
  }

  // ---- write O partial (bf16, no division) ----
  u16* op = opart + (size_t)(bq * 5 + c) * 1024;
  const int d = w * 16 + l15;
  #pragma unroll
  for (int r = 0; r < 4; ++r) {
    const int row = rg * 4 + r;
    op[row * 64 + d] = f2bf(accO[r]);
  }
}

// ---------------- attn reduce: sum 5 chunk partials, divide, -> aout bf16 ----------------
__global__ __launch_bounds__(256) void attn_reduce(
    const u16* __restrict__ opart, const float* __restrict__ dpart,
    u16* __restrict__ aout)
{
  const int bq = blockIdx.x;                 // (b*12+h)*36+qt
  const int t = threadIdx.x;
  const int b = bq / 432;
  const int h = (bq / 36) % 12;
  const int qt = bq % 36;
  const u16* ob = opart + (size_t)bq * 5 * 1024;
  const float* db = dpart + (size_t)bq * 5 * 16;
  const int e = t * 4;
  const int row = e >> 6, d0 = e & 63;
  float dn = 0.f;
  #pragma unroll
  for (int c = 0; c < 5; ++c) dn += db[c * 16 + row];
  float o0 = 0.f, o1 = 0.f, o2 = 0.f, o3 = 0.f;
  #pragma unroll
  for (int c = 0; c < 5; ++c) {
    uint2 v = *(const uint2*)&ob[c * 1024 + e];
    o0 += bf2f((u16)(v.x & 0xFFFF)); o1 += bf2f((u16)(v.x >> 16));
    o2 += bf2f((u16)(v.y & 0xFFFF)); o3 += bf2f((u16)(v.y >> 16));
  }
  const float inv = 1.f / dn;
  uint2 ov;
  ov.x = (u32)f2bf(o0 * inv) | ((u32)f2bf(o1 * inv) << 16);
  ov.y = (u32)f2bf(o2 * inv) | ((u32)f2bf(o3 * inv) << 16);
  *(uint2*)&aout[((size_t)(b * 576 + qt * 16 + row)) * 768 + h * 64 + d0] = ov;
}

// ---------------- host launcher ----------------
extern "C" void kernel_launch(void* const* d_in, const int* in_sizes, int n_in,
                              void* d_out, int out_size, void* d_ws, size_t ws_size,
                              hipStream_t stream)
{
  const float* x      = (const float*)d_in[0];
  const float* qkv_w  = (const float*)d_in[1];
  const float* proj_w = (const float*)d_in[2];
  const float* proj_b = (const float*)d_in[3];
  float* out = (float*)d_out;

  char* ws = (char*)d_ws;
  size_t off = 0;
  auto alloc = [&](size_t bytes) -> void* {
    void* p = ws + off;
    off += (bytes + 255) & ~(size_t)255;
    return p;
  };
  u16* xb    = (u16*)alloc((size_t)23040 * 768 * 2);    // x bf16
  u16* wqb   = (u16*)alloc((size_t)2304 * 768 * 2);     // qkv_w bf16
  u16* wpb   = (u16*)alloc((size_t)768 * 768 * 2);      // proj_w bf16
  u16* qbuf  = (u16*)alloc((size_t)96 * 576 * 64 * 2);  // q (pre-scaled 1/8)
  u16* vtb   = (u16*)alloc((size_t)96 * 64 * 2880 * 2); // v^T, full 2880 keys
  u16* aout  = (u16*)alloc((size_t)4608 * 768 * 2);     // attention output (B*hw, C)
  u16* opart = (u16*)alloc((size_t)17280 * 1024 * 2);   // per-chunk O partials (bf16)
  float* dpart = (float*)alloc((size_t)17280 * 16 * 4); // per-chunk denom partials
  // k (35.4 MB) lives inside d_out during the early phases; proj +
  // passthrough overwrite d_out only after attn has consumed it.
  u16* kbuf = (u16*)d_out;

  cvt_kernel<<<17280, 256, 0, stream>>>(x, xb, 17694720 / 4);
  cvt_kernel<<<1728, 256, 0, stream>>>(qkv_w, wqb, 1769472 / 4);
  cvt_kernel<<<576, 256, 0, stream>>>(proj_w, wpb, 589824 / 4);
  gemm_nt<0><<<dim3(18, 180), 256, 0, stream>>>(xb, wqb, nullptr,
                                                qbuf, kbuf, vtb, nullptr);
  attn_kernel<<<17280, 256, 0, stream>>>(qbuf, kbuf, vtb, opart, dpart);
  attn_reduce<<<3456, 256, 0, stream>>>(opart, dpart, aout);
  gemm_nt<1><<<dim3(6, 36), 256, 0, stream>>>(aout, wpb, proj_b,
                                              nullptr, nullptr, nullptr, out);
  copy_tail_kernel<<<13824, 256, 0, stream>>>(x, out);
}

// Round 14
// 471.403 us; speedup vs baseline: 1.1193x; 1.1193x over previous
//
#include <hip/hip_runtime.h>
#include <hip/hip_bf16.h>

// Attention_89335319756981 — MI355X bf16-MFMA implementation, round 14.
// B=8, N=2880 (hw=576 + T=4 frames of 576), C=768, H=12, hd=64, TOPK=32.
//
// Round-14 (base = round 10, best so far):
//  - cvt-x and tail-copy fused (x read once); kbuf moved into ws.
//  - opart partials bf16 (halves attn partial write + reduce read).
//  - attn kernel otherwise identical to round 10 (no spill, VGPR 36).

using s16x8 = __attribute__((ext_vector_type(8))) short;
using f32x4 = __attribute__((ext_vector_type(4))) float;
typedef unsigned short u16;
typedef unsigned int u32;

#define MFMA_B16(A,B,C) __builtin_amdgcn_mfma_f32_16x16x32_bf16(A,B,C,0,0,0)

__device__ __forceinline__ u16 f2bf(float f) {
  unsigned u = __float_as_uint(f);
  u += 0x7FFFu + ((u >> 16) & 1u);          // RNE, no NaN inputs here
  return (u16)(u >> 16);
}
__device__ __forceinline__ float bf2f(u16 h) {
  return __uint_as_float(((unsigned)h) << 16);
}
__device__ __forceinline__ int lanes_below(unsigned long long m) {
  return __builtin_amdgcn_mbcnt_hi((unsigned)(m >> 32),
         __builtin_amdgcn_mbcnt_lo((unsigned)m, 0));
}
__device__ __forceinline__ void stage16(const u16* __restrict__ g, u16* l) {
  __builtin_amdgcn_global_load_lds(
      (const __attribute__((address_space(1))) unsigned int*)g,
      (__attribute__((address_space(3))) unsigned int*)l, 16, 0, 0);
}
// sum of the two bf16 halves of a packed dword (zeros contribute 0)
__device__ __forceinline__ float sumpair(u32 d) {
  return __uint_as_float(d << 16) + __uint_as_float(d & 0xFFFF0000u);
}

// ---------------- fused: x -> bf16 (all rows) + tail passthrough copy ----------------
// one read of x; writes xb (bf16) and out rows [576,2880) per batch (f32).
__global__ __launch_bounds__(256) void cvt_x_tail(const float* __restrict__ x,
                                                  u16* __restrict__ xb,
                                                  float* __restrict__ out) {
  const int i = blockIdx.x * blockDim.x + threadIdx.x;  // float4 units, 4423680 total
  float4 v = ((const float4*)x)[i];
  unsigned lo = (unsigned)f2bf(v.x) | ((unsigned)f2bf(v.y) << 16);
  unsigned hi = (unsigned)f2bf(v.z) | ((unsigned)f2bf(v.w) << 16);
  uint2 o; o.x = lo; o.y = hi;
  ((uint2*)xb)[i] = o;
  const int b = i / 552960;                 // 2880*768/4 per batch
  const int off = i - b * 552960;
  if (off >= 110592)                        // rows >= 576: exact f32 passthrough
    ((float4*)out)[i] = v;
}

// ---------------- f32 -> bf16 convert (weights) ----------------
__global__ __launch_bounds__(256) void cvt_kernel(const float* __restrict__ src,
                                                  u16* __restrict__ dst, int n4) {
  int i = blockIdx.x * blockDim.x + threadIdx.x;
  if (i >= n4) return;
  float4 v = ((const float4*)src)[i];
  unsigned lo = (unsigned)f2bf(v.x) | ((unsigned)f2bf(v.y) << 16);
  unsigned hi = (unsigned)f2bf(v.z) | ((unsigned)f2bf(v.w) << 16);
  uint2 o; o.x = lo; o.y = hi;
  ((uint2*)dst)[i] = o;
}

// ---------------- NT GEMM, 128x128 tile, BK=64, global_load_lds ----------------
template<int MODE>
__global__ __launch_bounds__(256) void gemm_nt(
    const u16* __restrict__ A, const u16* __restrict__ Bw,
    const float* __restrict__ bias,
    u16* __restrict__ qbuf, u16* __restrict__ kbuf,
    u16* __restrict__ vtb, float* __restrict__ fout)
{
  __shared__ __align__(16) u16 smem[128 * 128];   // 32KB: sA|sB, reused for vT
  u16* sA = smem;
  u16* sB = smem + 128 * 64;
  const int n0 = blockIdx.x * 128;
  const int m0 = blockIdx.y * 128;
  if (MODE == 0 && n0 < 768) {
    const int s = m0 % 2880;
    if (s >= 576 && s + 128 <= 2880) return;
  }
  const int tid = threadIdx.x;
  const int w = tid >> 6, lane = tid & 63;
  const int l15 = lane & 15, rg = lane >> 4;
  const int ko = rg * 8;
  const int mq = (w >> 1) * 64, nq = (w & 1) * 64;
  const int trow = tid >> 3, tcol = (tid & 7) * 8;

  f32x4 z = {0.f, 0.f, 0.f, 0.f};
  f32x4 acc[4][4];
  #pragma unroll
  for (int i = 0; i < 4; ++i)
    #pragma unroll
    for (int j = 0; j < 4; ++j) acc[i][j] = z;

  for (int k0 = 0; k0 < 768; k0 += 64) {
    __syncthreads();
    #pragma unroll
    for (int i = 0; i < 4; ++i) {
      stage16(&A[(size_t)(m0 + trow + i * 32) * 768 + k0 + tcol],
              &sA[(trow + i * 32) * 64 + tcol]);
      stage16(&Bw[(size_t)(n0 + trow + i * 32) * 768 + k0 + tcol],
              &sB[(trow + i * 32) * 64 + tcol]);
    }
    __syncthreads();
    #pragma unroll
    for (int kk = 0; kk < 2; ++kk) {
      const int ko2 = kk * 32 + ko;
      s16x8 af[4], bf[4];
      #pragma unroll
      for (int i = 0; i < 4; ++i) {
        af[i] = *(const s16x8*)&sA[(mq + i * 16 + l15) * 64 + ko2];
        bf[i] = *(const s16x8*)&sB[(nq + i * 16 + l15) * 64 + ko2];
      }
      #pragma unroll
      for (int mi = 0; mi < 4; ++mi)
        #pragma unroll
        for (int ni = 0; ni < 4; ++ni)
          acc[mi][ni] = MFMA_B16(af[mi], bf[ni], acc[mi][ni]);
    }
  }

  if (MODE == 0) {
    const int which = n0 / 768;
    const int nb = n0 % 768;
    if (which == 2) {
      __syncthreads();
      #pragma unroll
      for (int mi = 0; mi < 4; ++mi)
        #pragma unroll
        for (int ni = 0; ni < 4; ++ni)
          #pragma unroll
          for (int r = 0; r < 4; ++r)
            smem[(mq + mi * 16 + rg * 4 + r) * 128 + nq + ni * 16 + l15] =
                f2bf(acc[mi][ni][r]);
      __syncthreads();
      const int c = tid & 127, kh = tid >> 7;
      const int gm0 = m0 + kh * 64;
      const int bb = gm0 / 2880, rr0 = gm0 - bb * 2880;
      const int ng = nb + c;
      const int hh = ng >> 6, dd = ng & 63;
      u16* dst = vtb + ((size_t)((bb * 12 + hh) * 64 + dd)) * 2880 + rr0;
      #pragma unroll
      for (int seg = 0; seg < 4; ++seg) {
        u16 tmp[16];
        #pragma unroll
        for (int i = 0; i < 16; ++i)
          tmp[i] = smem[(kh * 64 + seg * 16 + i) * 128 + c];
        *(int4*)&dst[seg * 16]     = *(const int4*)&tmp[0];
        *(int4*)&dst[seg * 16 + 8] = *(const int4*)&tmp[8];
      }
    } else {
      #pragma unroll
      for (int mi = 0; mi < 4; ++mi)
        #pragma unroll
        for (int ni = 0; ni < 4; ++ni)
          #pragma unroll
          for (int r = 0; r < 4; ++r) {
            const int gm = m0 + mq + mi * 16 + rg * 4 + r;
            const int b  = gm / 2880;
            const int rr = gm - b * 2880;
            const int ng = nb + nq + ni * 16 + l15;
            const int h  = ng >> 6, d = ng & 63;
            const float cc = acc[mi][ni][r];
            if (which == 0) {
              if (rr < 576)
                qbuf[((size_t)(b * 12 + h) * 576 + rr) * 64 + d] = f2bf(cc * 0.125f);
            } else {
              kbuf[((size_t)(b * 12 + h) * 2880 + rr) * 64 + d] = f2bf(cc);
            }
          }
    }
  } else {
    #pragma unroll
    for (int mi = 0; mi < 4; ++mi)
      #pragma unroll
      for (int ni = 0; ni < 4; ++ni)
        #pragma unroll
        for (int r = 0; r < 4; ++r) {
          const int gm = m0 + mq + mi * 16 + rg * 4 + r;
          const int gn = n0 + nq + ni * 16 + l15;
          const int b = gm / 576;
          const int q = gm - b * 576;
          fout[((size_t)b * 2880 + q) * 768 + gn] = acc[mi][ni][r] + bias[gn];
        }
  }
}

// ---------------- fused attention (round-10 structure): one key-chunk per block ----------------
// block = (b, h, 16 q-rows, chunk c), 256 threads (4 waves), ~20.7KB LDS,
// 7 blocks/CU. Scores stored as exp (trunc bf16). Top-32: 10-round ballot
// binary search on 10-bit compact keys, 2-row interleaved, vectorized key
// load/store. Partials: O_c bf16, denom_c f32 -> ws.
__global__ __launch_bounds__(256, 7) void attn_kernel(
    const u16* __restrict__ qbuf, const u16* __restrict__ kbuf,
    const u16* __restrict__ vtb,
    u16* __restrict__ opart, float* __restrict__ dpart)
{
  constexpr int PST = 648;                       // u16 stride: 1296B
  constexpr int BIAS = 0x3E80;                   // exp-bf16 code of ~0.25
  __shared__ __align__(16) u16 s_p[16 * PST];    // 20.7 KB exp(scores) / P

  const int bid = blockIdx.x;
  const int L = (bid & 7) * 2160 + (bid >> 3);   // 17280 = 8 XCD * 2160
  const int b   = L / 2160;
  const int rm  = L % 2160;
  const int c   = rm / 432;                      // chunk 0..4
  const int h   = (rm / 36) % 12;
  const int qt  = rm % 36;
  const int bh = b * 12 + h;
  const int q0 = qt * 16;
  const int bq = bh * 36 + qt;
  const int tid = threadIdx.x, w = tid >> 6, lane = tid & 63;
  const int l15 = lane & 15, rg = lane >> 4;
  const int ko = rg * 8;

  // zero the pad region u16[576..640) of each row (read by vector key loads)
  #pragma unroll
  for (int i = 0; i < 2; ++i) {
    const int idx = tid + 256 * i;               // 0..511
    const int row = idx >> 5, dw = idx & 31;
    *(u32*)&s_p[row * PST + 576 + dw * 2] = 0u;
  }

  // Q A-fragments for the block's 16 rows (2 K-halves)
  const u16* qp = qbuf + ((size_t)bh * 576 + q0) * 64;
  s16x8 aQ[2];
  aQ[0] = *(const s16x8*)&qp[l15 * 64 + ko];
  aQ[1] = *(const s16x8*)&qp[l15 * 64 + 32 + ko];

  const u16* kp = kbuf + (size_t)bh * 2880 * 64;
  const u16* vt = vtb + ((size_t)bh * 64 + w * 16 + l15) * 2880;
  f32x4 zz = {0.f, 0.f, 0.f, 0.f};
  f32x4 accO = zz;

  // ---- scores (stored as exp, truncated): wave w keys [w*144, w*144+144) ----
  #pragma unroll 3
  for (int t = 0; t < 9; ++t) {
    const int wk = w * 144 + t * 16;
    const u16* kr = kp + (size_t)(c * 576 + wk + l15) * 64 + ko;
    s16x8 kf0 = *(const s16x8*)&kr[0];
    s16x8 kf1 = *(const s16x8*)&kr[32];
    f32x4 a0 = zz;
    a0 = MFMA_B16(aQ[0], kf0, a0);
    a0 = MFMA_B16(aQ[1], kf1, a0);
    #pragma unroll
    for (int r = 0; r < 4; ++r)
      s_p[(rg * 4 + r) * PST + wk + l15] =
          (u16)(__float_as_uint(__expf(a0[r])) >> 16);   // truncate
  }
  __syncthreads();

  if (c == 0) {
    // ---- denom over qa: wave w owns rows w*4..w*4+3 (vectorized reads) ----
    #pragma unroll
    for (int ri = 0; ri < 4; ++ri) {
      const int q = w * 4 + ri;
      const u32* rp = (const u32*)&s_p[q * PST];
      uint4 dv = *(const uint4*)&rp[lane * 4];   // u16 idx 8L..8L+7
      u32 tl = rp[256 + lane];                   // u16 idx 512+2L..513+2L (pad=0)
      float s = sumpair(dv.x) + sumpair(dv.y) + sumpair(dv.z) + sumpair(dv.w)
              + sumpair(tl);
      #pragma unroll
      for (int off = 1; off < 64; off <<= 1) s += __shfl_xor(s, off);
      if (lane == 0) dpart[(size_t)(bq * 5 + c) * 16 + q] = s;
    }
    // no second barrier: PV and denom both only READ s_p
  } else {
    // ---- top-32, 2-row interleaved, 10-bit compact keys ----
    #pragma unroll
    for (int rp2 = 0; rp2 < 2; ++rp2) {
      const int qA = w * 4 + rp2 * 2, qB = qA + 1;
      u32* rpA = (u32*)&s_p[qA * PST];
      u32* rpB = (u32*)&s_p[qB * PST];
      unsigned kA[10], kB[10];
      {
        uint4 dA = *(const uint4*)&rpA[lane * 4];
        uint4 dB = *(const uint4*)&rpB[lane * 4];
        u32 tA = rpA[256 + lane], tB = rpB[256 + lane];
        kA[0]=dA.x&0xFFFF; kA[1]=dA.x>>16; kA[2]=dA.y&0xFFFF; kA[3]=dA.y>>16;
        kA[4]=dA.z&0xFFFF; kA[5]=dA.z>>16; kA[6]=dA.w&0xFFFF; kA[7]=dA.w>>16;
        kA[8]=tA&0xFFFF;   kA[9]=tA>>16;
        kB[0]=dB.x&0xFFFF; kB[1]=dB.x>>16; kB[2]=dB.y&0xFFFF; kB[3]=dB.y>>16;
        kB[4]=dB.z&0xFFFF; kB[5]=dB.z>>16; kB[6]=dB.w&0xFFFF; kB[7]=dB.w>>16;
        kB[8]=tB&0xFFFF;   kB[9]=tB>>16;
      }
      #pragma unroll
      for (int j = 0; j < 10; ++j) {             // compact: clamp(k-BIAS, 0, 1023)
        int tA2 = (int)kA[j] - BIAS;
        int tB2 = (int)kB[j] - BIAS;
        kA[j] = (unsigned)(tA2 < 0 ? 0 : (tA2 > 1023 ? 1023 : tA2));
        kB[j] = (unsigned)(tB2 < 0 ? 0 : (tB2 > 1023 ? 1023 : tB2));
      }
      unsigned pfA = 0, pfB = 0;
      #pragma unroll
      for (int bit = 9; bit >= 0; --bit) {
        const unsigned cA = pfA | (1u << bit), cB = pfB | (1u << bit);
        int nA = 0, nB = 0;
        #pragma unroll
        for (int j = 0; j < 10; ++j) {
          nA += __popcll(__ballot(kA[j] >= cA));
          nB += __popcll(__ballot(kB[j] >= cB));
        }
        if (nA >= 32) pfA = cA;
        if (nB >= 32) pfB = cB;
      }
      // ---- writeback per row: selected keep exp, others -> 0 (packed) ----
      #pragma unroll
      for (int rr = 0; rr < 2; ++rr) {
        const unsigned* k = rr ? kB : kA;
        const unsigned pf = rr ? pfB : pfA;
        u32* rp = rr ? rpB : rpA;
        const int q = rr ? qB : qA;
        int cnt_gt = 0;
        #pragma unroll
        for (int j = 0; j < 10; ++j)
          cnt_gt += __popcll(__ballot(k[j] > pf));
        const int rem = 32 - cnt_gt;             // tie slots (scan order)
        int run_eq = 0;
        u32 wd[5];
        float dsum = 0.f;
        #pragma unroll
        for (int j2 = 0; j2 < 5; ++j2) {
          u32 packed = 0;
          #pragma unroll
          for (int h2 = 0; h2 < 2; ++h2) {
            const int j = j2 * 2 + h2;
            const unsigned kj = k[j];
            unsigned long long eq = __ballot(kj == pf);
            const bool sel = (kj > pf) ||
                (kj == pf && run_eq + lanes_below(eq) < rem);
            run_eq += __popcll(eq);
            const u32 w16 = sel ? (kj + (u32)BIAS) : 0u;
            packed |= w16 << (16 * h2);
          }
          wd[j2] = packed;
          dsum += sumpair(packed);
        }
        *(uint4*)&rp[lane * 4] = *(const uint4*)&wd[0];
        rp[256 + lane] = wd[4];
        #pragma unroll
        for (int off = 1; off < 64; off <<= 1) dsum += __shfl_xor(dsum, off);
        if (lane == 0) dpart[(size_t)(bq * 5 + c) * 16 + q] = dsum;
      }
    }
    __syncthreads();   // P writeback visible before PV reads all rows
  }

  // ---- dense PV over this chunk: wave w owns output cols d = w*16..+15 ----
  #pragma unroll 3
  for (int k0 = 0; k0 < 576; k0 += 32) {
    s16x8 vf = *(const s16x8*)&vt[(size_t)c * 576 + k0 + ko];
    s16x8 pa = *(const s16x8*)&s_p[l15 * PST + k0 + ko];
    accO = MFMA_B16(pa, vf, accO);
  }

  // ---- write O partial (bf16, no division) ----
  u16* op = opart + (size_t)(bq * 5 + c) * 1024;
  const int d = w * 16 + l15;
  #pragma unroll
  for (int r = 0; r < 4; ++r) {
    const int row = rg * 4 + r;
    op[row * 64 + d] = f2bf(accO[r]);
  }
}

// ---------------- attn reduce: sum 5 chunk partials, divide, -> aout bf16 ----------------
__global__ __launch_bounds__(256) void attn_reduce(
    const u16* __restrict__ opart, const float* __restrict__ dpart,
    u16* __restrict__ aout)
{
  const int bq = blockIdx.x;                 // (b*12+h)*36+qt
  const int t = threadIdx.x;
  const int b = bq / 432;
  const int h = (bq / 36) % 12;
  const int qt = bq % 36;
  const u16* ob = opart + (size_t)bq * 5 * 1024;
  const float* db = dpart + (size_t)bq * 5 * 16;
  const int e = t * 4;
  const int row = e >> 6, d0 = e & 63;
  float dn = 0.f;
  #pragma unroll
  for (int c = 0; c < 5; ++c) dn += db[c * 16 + row];
  float o0 = 0.f, o1 = 0.f, o2 = 0.f, o3 = 0.f;
  #pragma unroll
  for (int c = 0; c < 5; ++c) {
    uint2 v = *(const uint2*)&ob[c * 1024 + e];
    o0 += bf2f((u16)(v.x & 0xFFFF)); o1 += bf2f((u16)(v.x >> 16));
    o2 += bf2f((u16)(v.y & 0xFFFF)); o3 += bf2f((u16)(v.y >> 16));
  }
  const float inv = 1.f / dn;
  uint2 ov;
  ov.x = (u32)f2bf(o0 * inv) | ((u32)f2bf(o1 * inv) << 16);
  ov.y = (u32)f2bf(o2 * inv) | ((u32)f2bf(o3 * inv) << 16);
  *(uint2*)&aout[((size_t)(b * 576 + qt * 16 + row)) * 768 + h * 64 + d0] = ov;
}

// ---------------- host launcher ----------------
extern "C" void kernel_launch(void* const* d_in, const int* in_sizes, int n_in,
                              void* d_out, int out_size, void* d_ws, size_t ws_size,
                              hipStream_t stream)
{
  const float* x      = (const float*)d_in[0];
  const float* qkv_w  = (const float*)d_in[1];
  const float* proj_w = (const float*)d_in[2];
  const float* proj_b = (const float*)d_in[3];
  float* out = (float*)d_out;

  char* ws = (char*)d_ws;
  size_t off = 0;
  auto alloc = [&](size_t bytes) -> void* {
    void* p = ws + off;
    off += (bytes + 255) & ~(size_t)255;
    return p;
  };
  u16* xb    = (u16*)alloc((size_t)23040 * 768 * 2);    // x bf16
  u16* wqb   = (u16*)alloc((size_t)2304 * 768 * 2);     // qkv_w bf16
  u16* wpb   = (u16*)alloc((size_t)768 * 768 * 2);      // proj_w bf16
  u16* qbuf  = (u16*)alloc((size_t)96 * 576 * 64 * 2);  // q (pre-scaled 1/8)
  u16* kbuf  = (u16*)alloc((size_t)96 * 2880 * 64 * 2); // k (now in ws)
  u16* vtb   = (u16*)alloc((size_t)96 * 64 * 2880 * 2); // v^T, full 2880 keys
  u16* aout  = (u16*)alloc((size_t)4608 * 768 * 2);     // attention output (B*hw, C)
  u16* opart = (u16*)alloc((size_t)17280 * 1024 * 2);   // per-chunk O partials (bf16)
  float* dpart = (float*)alloc((size_t)17280 * 16 * 4); // per-chunk denom partials

  cvt_x_tail<<<17280, 256, 0, stream>>>(x, xb, out);    // x read once: xb + tail copy
  cvt_kernel<<<1728, 256, 0, stream>>>(qkv_w, wqb, 1769472 / 4);
  cvt_kernel<<<576, 256, 0, stream>>>(proj_w, wpb, 589824 / 4);
  gemm_nt<0><<<dim3(18, 180), 256, 0, stream>>>(xb, wqb, nullptr,
                                                qbuf, kbuf, vtb, nullptr);
  attn_kernel<<<17280, 256, 0, stream>>>(qbuf, kbuf, vtb, opart, dpart);
  attn_reduce<<<3456, 256, 0, stream>>>(opart, dpart, aout);
  gemm_nt<1><<<dim3(6, 36), 256, 0, stream>>>(aout, wpb, proj_b,
                                              nullptr, nullptr, nullptr, out);
}

// Round 15
// 466.546 us; speedup vs baseline: 1.1309x; 1.0104x over previous
//
#include <hip/hip_runtime.h>
#include <hip/hip_bf16.h>

// Attention_89335319756981 — MI355X bf16-MFMA implementation, round 15.
// B=8, N=2880 (hw=576 + T=4 frames of 576), C=768, H=12, hd=64, TOPK=32.
//
// Round-15 (base = round 14, best so far: 471.4 us):
//  - attn: s_setprio(1) wrapped around the scores (MFMA+exp) loop and the
//    PV MFMA loop (T5; +4-7% on phase-diverse attn blocks per m191).
//  - gemm0/gemm1: 1D grid + bijective XCD swizzle (same-A-panel blocks on
//    one XCD -> L2-local A reads). 3240=8*405, 216=8*27 exact.

using s16x8 = __attribute__((ext_vector_type(8))) short;
using f32x4 = __attribute__((ext_vector_type(4))) float;
typedef unsigned short u16;
typedef unsigned int u32;

#define MFMA_B16(A,B,C) __builtin_amdgcn_mfma_f32_16x16x32_bf16(A,B,C,0,0,0)

__device__ __forceinline__ u16 f2bf(float f) {
  unsigned u = __float_as_uint(f);
  u += 0x7FFFu + ((u >> 16) & 1u);          // RNE, no NaN inputs here
  return (u16)(u >> 16);
}
__device__ __forceinline__ float bf2f(u16 h) {
  return __uint_as_float(((unsigned)h) << 16);
}
__device__ __forceinline__ int lanes_below(unsigned long long m) {
  return __builtin_amdgcn_mbcnt_hi((unsigned)(m >> 32),
         __builtin_amdgcn_mbcnt_lo((unsigned)m, 0));
}
__device__ __forceinline__ void stage16(const u16* __restrict__ g, u16* l) {
  __builtin_amdgcn_global_load_lds(
      (const __attribute__((address_space(1))) unsigned int*)g,
      (__attribute__((address_space(3))) unsigned int*)l, 16, 0, 0);
}
// sum of the two bf16 halves of a packed dword (zeros contribute 0)
__device__ __forceinline__ float sumpair(u32 d) {
  return __uint_as_float(d << 16) + __uint_as_float(d & 0xFFFF0000u);
}

// ---------------- fused: x -> bf16 (all rows) + tail passthrough copy ----------------
__global__ __launch_bounds__(256) void cvt_x_tail(const float* __restrict__ x,
                                                  u16* __restrict__ xb,
                                                  float* __restrict__ out) {
  const int i = blockIdx.x * blockDim.x + threadIdx.x;  // float4 units, 4423680 total
  float4 v = ((const float4*)x)[i];
  unsigned lo = (unsigned)f2bf(v.x) | ((unsigned)f2bf(v.y) << 16);
  unsigned hi = (unsigned)f2bf(v.z) | ((unsigned)f2bf(v.w) << 16);
  uint2 o; o.x = lo; o.y = hi;
  ((uint2*)xb)[i] = o;
  const int b = i / 552960;                 // 2880*768/4 per batch
  const int off = i - b * 552960;
  if (off >= 110592)                        // rows >= 576: exact f32 passthrough
    ((float4*)out)[i] = v;
}

// ---------------- f32 -> bf16 convert (weights) ----------------
__global__ __launch_bounds__(256) void cvt_kernel(const float* __restrict__ src,
                                                  u16* __restrict__ dst, int n4) {
  int i = blockIdx.x * blockDim.x + threadIdx.x;
  if (i >= n4) return;
  float4 v = ((const float4*)src)[i];
  unsigned lo = (unsigned)f2bf(v.x) | ((unsigned)f2bf(v.y) << 16);
  unsigned hi = (unsigned)f2bf(v.z) | ((unsigned)f2bf(v.w) << 16);
  uint2 o; o.x = lo; o.y = hi;
  ((uint2*)dst)[i] = o;
}

// ---------------- NT GEMM, 128x128 tile, BK=64, global_load_lds ----------------
// 1D grid, bijective XCD swizzle: L = (bid%8)*(nwg/8) + bid/8.
// MODE 0: nwg=3240 (18 x 180). MODE 1: nwg=216 (6 x 36).
template<int MODE>
__global__ __launch_bounds__(256) void gemm_nt(
    const u16* __restrict__ A, const u16* __restrict__ Bw,
    const float* __restrict__ bias,
    u16* __restrict__ qbuf, u16* __restrict__ kbuf,
    u16* __restrict__ vtb, float* __restrict__ fout)
{
  __shared__ __align__(16) u16 smem[128 * 128];   // 32KB: sA|sB, reused for vT
  u16* sA = smem;
  u16* sB = smem + 128 * 64;
  constexpr int NX = (MODE == 0) ? 18 : 6;
  constexpr int QX = (MODE == 0) ? 405 : 27;      // nwg / 8 (exact)
  const int bid = blockIdx.x;
  const int Lw = (bid & 7) * QX + (bid >> 3);     // bijective XCD remap
  const int n0 = (Lw % NX) * 128;
  const int m0 = (Lw / NX) * 128;
  if (MODE == 0 && n0 < 768) {
    const int s = m0 % 2880;
    if (s >= 576 && s + 128 <= 2880) return;
  }
  const int tid = threadIdx.x;
  const int w = tid >> 6, lane = tid & 63;
  const int l15 = lane & 15, rg = lane >> 4;
  const int ko = rg * 8;
  const int mq = (w >> 1) * 64, nq = (w & 1) * 64;
  const int trow = tid >> 3, tcol = (tid & 7) * 8;

  f32x4 z = {0.f, 0.f, 0.f, 0.f};
  f32x4 acc[4][4];
  #pragma unroll
  for (int i = 0; i < 4; ++i)
    #pragma unroll
    for (int j = 0; j < 4; ++j) acc[i][j] = z;

  for (int k0 = 0; k0 < 768; k0 += 64) {
    __syncthreads();
    #pragma unroll
    for (int i = 0; i < 4; ++i) {
      stage16(&A[(size_t)(m0 + trow + i * 32) * 768 + k0 + tcol],
              &sA[(trow + i * 32) * 64 + tcol]);
      stage16(&Bw[(size_t)(n0 + trow + i * 32) * 768 + k0 + tcol],
              &sB[(trow + i * 32) * 64 + tcol]);
    }
    __syncthreads();
    #pragma unroll
    for (int kk = 0; kk < 2; ++kk) {
      const int ko2 = kk * 32 + ko;
      s16x8 af[4], bf[4];
      #pragma unroll
      for (int i = 0; i < 4; ++i) {
        af[i] = *(const s16x8*)&sA[(mq + i * 16 + l15) * 64 + ko2];
        bf[i] = *(const s16x8*)&sB[(nq + i * 16 + l15) * 64 + ko2];
      }
      #pragma unroll
      for (int mi = 0; mi < 4; ++mi)
        #pragma unroll
        for (int ni = 0; ni < 4; ++ni)
          acc[mi][ni] = MFMA_B16(af[mi], bf[ni], acc[mi][ni]);
    }
  }

  if (MODE == 0) {
    const int which = n0 / 768;
    const int nb = n0 % 768;
    if (which == 2) {
      __syncthreads();
      #pragma unroll
      for (int mi = 0; mi < 4; ++mi)
        #pragma unroll
        for (int ni = 0; ni < 4; ++ni)
          #pragma unroll
          for (int r = 0; r < 4; ++r)
            smem[(mq + mi * 16 + rg * 4 + r) * 128 + nq + ni * 16 + l15] =
                f2bf(acc[mi][ni][r]);
      __syncthreads();
      const int c = tid & 127, kh = tid >> 7;
      const int gm0 = m0 + kh * 64;
      const int bb = gm0 / 2880, rr0 = gm0 - bb * 2880;
      const int ng = nb + c;
      const int hh = ng >> 6, dd = ng & 63;
      u16* dst = vtb + ((size_t)((bb * 12 + hh) * 64 + dd)) * 2880 + rr0;
      #pragma unroll
      for (int seg = 0; seg < 4; ++seg) {
        u16 tmp[16];
        #pragma unroll
        for (int i = 0; i < 16; ++i)
          tmp[i] = smem[(kh * 64 + seg * 16 + i) * 128 + c];
        *(int4*)&dst[seg * 16]     = *(const int4*)&tmp[0];
        *(int4*)&dst[seg * 16 + 8] = *(const int4*)&tmp[8];
      }
    } else {
      #pragma unroll
      for (int mi = 0; mi < 4; ++mi)
        #pragma unroll
        for (int ni = 0; ni < 4; ++ni)
          #pragma unroll
          for (int r = 0; r < 4; ++r) {
            const int gm = m0 + mq + mi * 16 + rg * 4 + r;
            const int b  = gm / 2880;
            const int rr = gm - b * 2880;
            const int ng = nb + nq + ni * 16 + l15;
            const int h  = ng >> 6, d = ng & 63;
            const float cc = acc[mi][ni][r];
            if (which == 0) {
              if (rr < 576)
                qbuf[((size_t)(b * 12 + h) * 576 + rr) * 64 + d] = f2bf(cc * 0.125f);
            } else {
              kbuf[((size_t)(b * 12 + h) * 2880 + rr) * 64 + d] = f2bf(cc);
            }
          }
    }
  } else {
    #pragma unroll
    for (int mi = 0; mi < 4; ++mi)
      #pragma unroll
      for (int ni = 0; ni < 4; ++ni)
        #pragma unroll
        for (int r = 0; r < 4; ++r) {
          const int gm = m0 + mq + mi * 16 + rg * 4 + r;
          const int gn = n0 + nq + ni * 16 + l15;
          const int b = gm / 576;
          const int q = gm - b * 576;
          fout[((size_t)b * 2880 + q) * 768 + gn] = acc[mi][ni][r] + bias[gn];
        }
  }
}

// ---------------- fused attention (round-10 structure + setprio): one key-chunk per block ----------------
__global__ __launch_bounds__(256, 7) void attn_kernel(
    const u16* __restrict__ qbuf, const u16* __restrict__ kbuf,
    const u16* __restrict__ vtb,
    u16* __restrict__ opart, float* __restrict__ dpart)
{
  constexpr int PST = 648;                       // u16 stride: 1296B
  constexpr int BIAS = 0x3E80;                   // exp-bf16 code of ~0.25
  __shared__ __align__(16) u16 s_p[16 * PST];    // 20.7 KB exp(scores) / P

  const int bid = blockIdx.x;
  const int L = (bid & 7) * 2160 + (bid >> 3);   // 17280 = 8 XCD * 2160
  const int b   = L / 2160;
  const int rm  = L % 2160;
  const int c   = rm / 432;                      // chunk 0..4
  const int h   = (rm / 36) % 12;
  const int qt  = rm % 36;
  const int bh = b * 12 + h;
  const int q0 = qt * 16;
  const int bq = bh * 36 + qt;
  const int tid = threadIdx.x, w = tid >> 6, lane = tid & 63;
  const int l15 = lane & 15, rg = lane >> 4;
  const int ko = rg * 8;

  // zero the pad region u16[576..640) of each row (read by vector key loads)
  #pragma unroll
  for (int i = 0; i < 2; ++i) {
    const int idx = tid + 256 * i;               // 0..511
    const int row = idx >> 5, dw = idx & 31;
    *(u32*)&s_p[row * PST + 576 + dw * 2] = 0u;
  }

  // Q A-fragments for the block's 16 rows (2 K-halves)
  const u16* qp = qbuf + ((size_t)bh * 576 + q0) * 64;
  s16x8 aQ[2];
  aQ[0] = *(const s16x8*)&qp[l15 * 64 + ko];
  aQ[1] = *(const s16x8*)&qp[l15 * 64 + 32 + ko];

  const u16* kp = kbuf + (size_t)bh * 2880 * 64;
  const u16* vt = vtb + ((size_t)bh * 64 + w * 16 + l15) * 2880;
  f32x4 zz = {0.f, 0.f, 0.f, 0.f};
  f32x4 accO = zz;

  // ---- scores (stored as exp, truncated): wave w keys [w*144, w*144+144) ----
  __builtin_amdgcn_s_setprio(1);
  #pragma unroll 3
  for (int t = 0; t < 9; ++t) {
    const int wk = w * 144 + t * 16;
    const u16* kr = kp + (size_t)(c * 576 + wk + l15) * 64 + ko;
    s16x8 kf0 = *(const s16x8*)&kr[0];
    s16x8 kf1 = *(const s16x8*)&kr[32];
    f32x4 a0 = zz;
    a0 = MFMA_B16(aQ[0], kf0, a0);
    a0 = MFMA_B16(aQ[1], kf1, a0);
    #pragma unroll
    for (int r = 0; r < 4; ++r)
      s_p[(rg * 4 + r) * PST + wk + l15] =
          (u16)(__float_as_uint(__expf(a0[r])) >> 16);   // truncate
  }
  __builtin_amdgcn_s_setprio(0);
  __syncthreads();

  if (c == 0) {
    // ---- denom over qa: wave w owns rows w*4..w*4+3 (vectorized reads) ----
    #pragma unroll
    for (int ri = 0; ri < 4; ++ri) {
      const int q = w * 4 + ri;
      const u32* rp = (const u32*)&s_p[q * PST];
      uint4 dv = *(const uint4*)&rp[lane * 4];   // u16 idx 8L..8L+7
      u32 tl = rp[256 + lane];                   // u16 idx 512+2L..513+2L (pad=0)
      float s = sumpair(dv.x) + sumpair(dv.y) + sumpair(dv.z) + sumpair(dv.w)
              + sumpair(tl);
      #pragma unroll
      for (int off = 1; off < 64; off <<= 1) s += __shfl_xor(s, off);
      if (lane == 0) dpart[(size_t)(bq * 5 + c) * 16 + q] = s;
    }
    // no second barrier: PV and denom both only READ s_p
  } else {
    // ---- top-32, 2-row interleaved, 10-bit compact keys ----
    #pragma unroll
    for (int rp2 = 0; rp2 < 2; ++rp2) {
      const int qA = w * 4 + rp2 * 2, qB = qA + 1;
      u32* rpA = (u32*)&s_p[qA * PST];
      u32* rpB = (u32*)&s_p[qB * PST];
      unsigned kA[10], kB[10];
      {
        uint4 dA = *(const uint4*)&rpA[lane * 4];
        uint4 dB = *(const uint4*)&rpB[lane * 4];
        u32 tA = rpA[256 + lane], tB = rpB[256 + lane];
        kA[0]=dA.x&0xFFFF; kA[1]=dA.x>>16; kA[2]=dA.y&0xFFFF; kA[3]=dA.y>>16;
        kA[4]=dA.z&0xFFFF; kA[5]=dA.z>>16; kA[6]=dA.w&0xFFFF; kA[7]=dA.w>>16;
        kA[8]=tA&0xFFFF;   kA[9]=tA>>16;
        kB[0]=dB.x&0xFFFF; kB[1]=dB.x>>16; kB[2]=dB.y&0xFFFF; kB[3]=dB.y>>16;
        kB[4]=dB.z&0xFFFF; kB[5]=dB.z>>16; kB[6]=dB.w&0xFFFF; kB[7]=dB.w>>16;
        kB[8]=tB&0xFFFF;   kB[9]=tB>>16;
      }
      #pragma unroll
      for (int j = 0; j < 10; ++j) {             // compact: clamp(k-BIAS, 0, 1023)
        int tA2 = (int)kA[j] - BIAS;
        int tB2 = (int)kB[j] - BIAS;
        kA[j] = (unsigned)(tA2 < 0 ? 0 : (tA2 > 1023 ? 1023 : tA2));
        kB[j] = (unsigned)(tB2 < 0 ? 0 : (tB2 > 1023 ? 1023 : tB2));
      }
      unsigned pfA = 0, pfB = 0;
      #pragma unroll
      for (int bit = 9; bit >= 0; --bit) {
        const unsigned cA = pfA | (1u << bit), cB = pfB | (1u << bit);
        int nA = 0, nB = 0;
        #pragma unroll
        for (int j = 0; j < 10; ++j) {
          nA += __popcll(__ballot(kA[j] >= cA));
          nB += __popcll(__ballot(kB[j] >= cB));
        }
        if (nA >= 32) pfA = cA;
        if (nB >= 32) pfB = cB;
      }
      // ---- writeback per row: selected keep exp, others -> 0 (packed) ----
      #pragma unroll
      for (int rr = 0; rr < 2; ++rr) {
        const unsigned* k = rr ? kB : kA;
        const unsigned pf = rr ? pfB : pfA;
        u32* rp = rr ? rpB : rpA;
        const int q = rr ? qB : qA;
        int cnt_gt = 0;
        #pragma unroll
        for (int j = 0; j < 10; ++j)
          cnt_gt += __popcll(__ballot(k[j] > pf));
        const int rem = 32 - cnt_gt;             // tie slots (scan order)
        int run_eq = 0;
        u32 wd[5];
        float dsum = 0.f;
        #pragma unroll
        for (int j2 = 0; j2 < 5; ++j2) {
          u32 packed = 0;
          #pragma unroll
          for (int h2 = 0; h2 < 2; ++h2) {
            const int j = j2 * 2 + h2;
            const unsigned kj = k[j];
            unsigned long long eq = __ballot(kj == pf);
            const bool sel = (kj > pf) ||
                (kj == pf && run_eq + lanes_below(eq) < rem);
            run_eq += __popcll(eq);
            const u32 w16 = sel ? (kj + (u32)BIAS) : 0u;
            packed |= w16 << (16 * h2);
          }
          wd[j2] = packed;
          dsum += sumpair(packed);
        }
        *(uint4*)&rp[lane * 4] = *(const uint4*)&wd[0];
        rp[256 + lane] = wd[4];
        #pragma unroll
        for (int off = 1; off < 64; off <<= 1) dsum += __shfl_xor(dsum, off);
        if (lane == 0) dpart[(size_t)(bq * 5 + c) * 16 + q] = dsum;
      }
    }
    __syncthreads();   // P writeback visible before PV reads all rows
  }

  // ---- dense PV over this chunk: wave w owns output cols d = w*16..+15 ----
  __builtin_amdgcn_s_setprio(1);
  #pragma unroll 3
  for (int k0 = 0; k0 < 576; k0 += 32) {
    s16x8 vf = *(const s16x8*)&vt[(size_t)c * 576 + k0 + ko];
    s16x8 pa = *(const s16x8*)&s_p[l15 * PST + k0 + ko];
    accO = MFMA_B16(pa, vf, accO);
  }
  __builtin_amdgcn_s_setprio(0);

  // ---- write O partial (bf16, no division) ----
  u16* op = opart + (size_t)(bq * 5 + c) * 1024;
  const int d = w * 16 + l15;
  #pragma unroll
  for (int r = 0; r < 4; ++r) {
    const int row = rg * 4 + r;
    op[row * 64 + d] = f2bf(accO[r]);
  }
}

// ---------------- attn reduce: sum 5 chunk partials, divide, -> aout bf16 ----------------
__global__ __launch_bounds__(256) void attn_reduce(
    const u16* __restrict__ opart, const float* __restrict__ dpart,
    u16* __restrict__ aout)
{
  const int bq = blockIdx.x;                 // (b*12+h)*36+qt
  const int t = threadIdx.x;
  const int b = bq / 432;
  const int h = (bq / 36) % 12;
  const int qt = bq % 36;
  const u16* ob = opart + (size_t)bq * 5 * 1024;
  const float* db = dpart + (size_t)bq * 5 * 16;
  const int e = t * 4;
  const int row = e >> 6, d0 = e & 63;
  float dn = 0.f;
  #pragma unroll
  for (int c = 0; c < 5; ++c) dn += db[c * 16 + row];
  float o0 = 0.f, o1 = 0.f, o2 = 0.f, o3 = 0.f;
  #pragma unroll
  for (int c = 0; c < 5; ++c) {
    uint2 v = *(const uint2*)&ob[c * 1024 + e];
    o0 += bf2f((u16)(v.x & 0xFFFF)); o1 += bf2f((u16)(v.x >> 16));
    o2 += bf2f((u16)(v.y & 0xFFFF)); o3 += bf2f((u16)(v.y >> 16));
  }
  const float inv = 1.f / dn;
  uint2 ov;
  ov.x = (u32)f2bf(o0 * inv) | ((u32)f2bf(o1 * inv) << 16);
  ov.y = (u32)f2bf(o2 * inv) | ((u32)f2bf(o3 * inv) << 16);
  *(uint2*)&aout[((size_t)(b * 576 + qt * 16 + row)) * 768 + h * 64 + d0] = ov;
}

// ---------------- host launcher ----------------
extern "C" void kernel_launch(void* const* d_in, const int* in_sizes, int n_in,
                              void* d_out, int out_size, void* d_ws, size_t ws_size,
                              hipStream_t stream)
{
  const float* x      = (const float*)d_in[0];
  const float* qkv_w  = (const float*)d_in[1];
  const float* proj_w = (const float*)d_in[2];
  const float* proj_b = (const float*)d_in[3];
  float* out = (float*)d_out;

  char* ws = (char*)d_ws;
  size_t off = 0;
  auto alloc = [&](size_t bytes) -> void* {
    void* p = ws + off;
    off += (bytes + 255) & ~(size_t)255;
    return p;
  };
  u16* xb    = (u16*)alloc((size_t)23040 * 768 * 2);    // x bf16
  u16* wqb   = (u16*)alloc((size_t)2304 * 768 * 2);     // qkv_w bf16
  u16* wpb   = (u16*)alloc((size_t)768 * 768 * 2);      // proj_w bf16
  u16* qbuf  = (u16*)alloc((size_t)96 * 576 * 64 * 2);  // q (pre-scaled 1/8)
  u16* kbuf  = (u16*)alloc((size_t)96 * 2880 * 64 * 2); // k
  u16* vtb   = (u16*)alloc((size_t)96 * 64 * 2880 * 2); // v^T, full 2880 keys
  u16* aout  = (u16*)alloc((size_t)4608 * 768 * 2);     // attention output (B*hw, C)
  u16* opart = (u16*)alloc((size_t)17280 * 1024 * 2);   // per-chunk O partials (bf16)
  float* dpart = (float*)alloc((size_t)17280 * 16 * 4); // per-chunk denom partials

  cvt_x_tail<<<17280, 256, 0, stream>>>(x, xb, out);    // x read once: xb + tail copy
  cvt_kernel<<<1728, 256, 0, stream>>>(qkv_w, wqb, 1769472 / 4);
  cvt_kernel<<<576, 256, 0, stream>>>(proj_w, wpb, 589824 / 4);
  gemm_nt<0><<<3240, 256, 0, stream>>>(xb, wqb, nullptr,
                                       qbuf, kbuf, vtb, nullptr);
  attn_kernel<<<17280, 256, 0, stream>>>(qbuf, kbuf, vtb, opart, dpart);
  attn_reduce<<<3456, 256, 0, stream>>>(opart, dpart, aout);
  gemm_nt<1><<<216, 256, 0, stream>>>(aout, wpb, proj_b,
                                      nullptr, nullptr, nullptr, out);
}

// Round 16
// 464.306 us; speedup vs baseline: 1.1364x; 1.0048x over previous
//
#include <hip/hip_runtime.h>
#include <hip/hip_bf16.h>

// Attention_89335319756981 — MI355X bf16-MFMA implementation, round 16.
// B=8, N=2880 (hw=576 + T=4 frames of 576), C=768, H=12, hd=64, TOPK=32.
//
// Round-16 (base = round 15, best so far: 466.5 us):
//  - attn topk: 9 keys/lane (u16 tail load, pad keys + pad-zero init deleted);
//    search tracks cnt(>=pf_final); writeback takes a ballot-free pure-VALU
//    fast path when there is no boundary tie (cnt==32), exact tie path kept.

using s16x8 = __attribute__((ext_vector_type(8))) short;
using f32x4 = __attribute__((ext_vector_type(4))) float;
typedef unsigned short u16;
typedef unsigned int u32;

#define MFMA_B16(A,B,C) __builtin_amdgcn_mfma_f32_16x16x32_bf16(A,B,C,0,0,0)

__device__ __forceinline__ u16 f2bf(float f) {
  unsigned u = __float_as_uint(f);
  u += 0x7FFFu + ((u >> 16) & 1u);          // RNE, no NaN inputs here
  return (u16)(u >> 16);
}
__device__ __forceinline__ float bf2f(u16 h) {
  return __uint_as_float(((unsigned)h) << 16);
}
__device__ __forceinline__ int lanes_below(unsigned long long m) {
  return __builtin_amdgcn_mbcnt_hi((unsigned)(m >> 32),
         __builtin_amdgcn_mbcnt_lo((unsigned)m, 0));
}
__device__ __forceinline__ void stage16(const u16* __restrict__ g, u16* l) {
  __builtin_amdgcn_global_load_lds(
      (const __attribute__((address_space(1))) unsigned int*)g,
      (__attribute__((address_space(3))) unsigned int*)l, 16, 0, 0);
}
// sum of the two bf16 halves of a packed dword (zeros contribute 0)
__device__ __forceinline__ float sumpair(u32 d) {
  return __uint_as_float(d << 16) + __uint_as_float(d & 0xFFFF0000u);
}

// ---------------- fused: x -> bf16 (all rows) + tail passthrough copy ----------------
__global__ __launch_bounds__(256) void cvt_x_tail(const float* __restrict__ x,
                                                  u16* __restrict__ xb,
                                                  float* __restrict__ out) {
  const int i = blockIdx.x * blockDim.x + threadIdx.x;  // float4 units, 4423680 total
  float4 v = ((const float4*)x)[i];
  unsigned lo = (unsigned)f2bf(v.x) | ((unsigned)f2bf(v.y) << 16);
  unsigned hi = (unsigned)f2bf(v.z) | ((unsigned)f2bf(v.w) << 16);
  uint2 o; o.x = lo; o.y = hi;
  ((uint2*)xb)[i] = o;
  const int b = i / 552960;                 // 2880*768/4 per batch
  const int off = i - b * 552960;
  if (off >= 110592)                        // rows >= 576: exact f32 passthrough
    ((float4*)out)[i] = v;
}

// ---------------- f32 -> bf16 convert (weights) ----------------
__global__ __launch_bounds__(256) void cvt_kernel(const float* __restrict__ src,
                                                  u16* __restrict__ dst, int n4) {
  int i = blockIdx.x * blockDim.x + threadIdx.x;
  if (i >= n4) return;
  float4 v = ((const float4*)src)[i];
  unsigned lo = (unsigned)f2bf(v.x) | ((unsigned)f2bf(v.y) << 16);
  unsigned hi = (unsigned)f2bf(v.z) | ((unsigned)f2bf(v.w) << 16);
  uint2 o; o.x = lo; o.y = hi;
  ((uint2*)dst)[i] = o;
}

// ---------------- NT GEMM, 128x128 tile, BK=64, global_load_lds ----------------
// 1D grid, bijective XCD swizzle: L = (bid%8)*(nwg/8) + bid/8.
template<int MODE>
__global__ __launch_bounds__(256) void gemm_nt(
    const u16* __restrict__ A, const u16* __restrict__ Bw,
    const float* __restrict__ bias,
    u16* __restrict__ qbuf, u16* __restrict__ kbuf,
    u16* __restrict__ vtb, float* __restrict__ fout)
{
  __shared__ __align__(16) u16 smem[128 * 128];   // 32KB: sA|sB, reused for vT
  u16* sA = smem;
  u16* sB = smem + 128 * 64;
  constexpr int NX = (MODE == 0) ? 18 : 6;
  constexpr int QX = (MODE == 0) ? 405 : 27;      // nwg / 8 (exact)
  const int bid = blockIdx.x;
  const int Lw = (bid & 7) * QX + (bid >> 3);     // bijective XCD remap
  const int n0 = (Lw % NX) * 128;
  const int m0 = (Lw / NX) * 128;
  if (MODE == 0 && n0 < 768) {
    const int s = m0 % 2880;
    if (s >= 576 && s + 128 <= 2880) return;
  }
  const int tid = threadIdx.x;
  const int w = tid >> 6, lane = tid & 63;
  const int l15 = lane & 15, rg = lane >> 4;
  const int ko = rg * 8;
  const int mq = (w >> 1) * 64, nq = (w & 1) * 64;
  const int trow = tid >> 3, tcol = (tid & 7) * 8;

  f32x4 z = {0.f, 0.f, 0.f, 0.f};
  f32x4 acc[4][4];
  #pragma unroll
  for (int i = 0; i < 4; ++i)
    #pragma unroll
    for (int j = 0; j < 4; ++j) acc[i][j] = z;

  for (int k0 = 0; k0 < 768; k0 += 64) {
    __syncthreads();
    #pragma unroll
    for (int i = 0; i < 4; ++i) {
      stage16(&A[(size_t)(m0 + trow + i * 32) * 768 + k0 + tcol],
              &sA[(trow + i * 32) * 64 + tcol]);
      stage16(&Bw[(size_t)(n0 + trow + i * 32) * 768 + k0 + tcol],
              &sB[(trow + i * 32) * 64 + tcol]);
    }
    __syncthreads();
    #pragma unroll
    for (int kk = 0; kk < 2; ++kk) {
      const int ko2 = kk * 32 + ko;
      s16x8 af[4], bf[4];
      #pragma unroll
      for (int i = 0; i < 4; ++i) {
        af[i] = *(const s16x8*)&sA[(mq + i * 16 + l15) * 64 + ko2];
        bf[i] = *(const s16x8*)&sB[(nq + i * 16 + l15) * 64 + ko2];
      }
      #pragma unroll
      for (int mi = 0; mi < 4; ++mi)
        #pragma unroll
        for (int ni = 0; ni < 4; ++ni)
          acc[mi][ni] = MFMA_B16(af[mi], bf[ni], acc[mi][ni]);
    }
  }

  if (MODE == 0) {
    const int which = n0 / 768;
    const int nb = n0 % 768;
    if (which == 2) {
      __syncthreads();
      #pragma unroll
      for (int mi = 0; mi < 4; ++mi)
        #pragma unroll
        for (int ni = 0; ni < 4; ++ni)
          #pragma unroll
          for (int r = 0; r < 4; ++r)
            smem[(mq + mi * 16 + rg * 4 + r) * 128 + nq + ni * 16 + l15] =
                f2bf(acc[mi][ni][r]);
      __syncthreads();
      const int c = tid & 127, kh = tid >> 7;
      const int gm0 = m0 + kh * 64;
      const int bb = gm0 / 2880, rr0 = gm0 - bb * 2880;
      const int ng = nb + c;
      const int hh = ng >> 6, dd = ng & 63;
      u16* dst = vtb + ((size_t)((bb * 12 + hh) * 64 + dd)) * 2880 + rr0;
      #pragma unroll
      for (int seg = 0; seg < 4; ++seg) {
        u16 tmp[16];
        #pragma unroll
        for (int i = 0; i < 16; ++i)
          tmp[i] = smem[(kh * 64 + seg * 16 + i) * 128 + c];
        *(int4*)&dst[seg * 16]     = *(const int4*)&tmp[0];
        *(int4*)&dst[seg * 16 + 8] = *(const int4*)&tmp[8];
      }
    } else {
      #pragma unroll
      for (int mi = 0; mi < 4; ++mi)
        #pragma unroll
        for (int ni = 0; ni < 4; ++ni)
          #pragma unroll
          for (int r = 0; r < 4; ++r) {
            const int gm = m0 + mq + mi * 16 + rg * 4 + r;
            const int b  = gm / 2880;
            const int rr = gm - b * 2880;
            const int ng = nb + nq + ni * 16 + l15;
            const int h  = ng >> 6, d = ng & 63;
            const float cc = acc[mi][ni][r];
            if (which == 0) {
              if (rr < 576)
                qbuf[((size_t)(b * 12 + h) * 576 + rr) * 64 + d] = f2bf(cc * 0.125f);
            } else {
              kbuf[((size_t)(b * 12 + h) * 2880 + rr) * 64 + d] = f2bf(cc);
            }
          }
    }
  } else {
    #pragma unroll
    for (int mi = 0; mi < 4; ++mi)
      #pragma unroll
      for (int ni = 0; ni < 4; ++ni)
        #pragma unroll
        for (int r = 0; r < 4; ++r) {
          const int gm = m0 + mq + mi * 16 + rg * 4 + r;
          const int gn = n0 + nq + ni * 16 + l15;
          const int b = gm / 576;
          const int q = gm - b * 576;
          fout[((size_t)b * 2880 + q) * 768 + gn] = acc[mi][ni][r] + bias[gn];
        }
  }
}

// ---------------- fused attention, round 16: one key-chunk per block ----------------
// block = (b, h, 16 q-rows, chunk c), 256 threads (4 waves), ~20.7KB LDS,
// 7 blocks/CU. Scores stored as exp (trunc bf16). Top-32: 10-round ballot
// binary search on 10-bit compact keys (9 keys/lane), 2-row interleaved;
// writeback: ballot-free fast path when no boundary tie (cnt(>=pf)==32),
// exact ballot tie path otherwise. Partials: O_c bf16, denom_c f32 -> ws.
__global__ __launch_bounds__(256, 7) void attn_kernel(
    const u16* __restrict__ qbuf, const u16* __restrict__ kbuf,
    const u16* __restrict__ vtb,
    u16* __restrict__ opart, float* __restrict__ dpart)
{
  constexpr int PST = 648;                       // u16 stride: 1296B
  constexpr int BIAS = 0x3E80;                   // exp-bf16 code of ~0.25
  __shared__ __align__(16) u16 s_p[16 * PST];    // 20.7 KB exp(scores) / P

  const int bid = blockIdx.x;
  const int L = (bid & 7) * 2160 + (bid >> 3);   // 17280 = 8 XCD * 2160
  const int b   = L / 2160;
  const int rm  = L % 2160;
  const int c   = rm / 432;                      // chunk 0..4
  const int h   = (rm / 36) % 12;
  const int qt  = rm % 36;
  const int bh = b * 12 + h;
  const int q0 = qt * 16;
  const int bq = bh * 36 + qt;
  const int tid = threadIdx.x, w = tid >> 6, lane = tid & 63;
  const int l15 = lane & 15, rg = lane >> 4;
  const int ko = rg * 8;

  // Q A-fragments for the block's 16 rows (2 K-halves)
  const u16* qp = qbuf + ((size_t)bh * 576 + q0) * 64;
  s16x8 aQ[2];
  aQ[0] = *(const s16x8*)&qp[l15 * 64 + ko];
  aQ[1] = *(const s16x8*)&qp[l15 * 64 + 32 + ko];

  const u16* kp = kbuf + (size_t)bh * 2880 * 64;
  const u16* vt = vtb + ((size_t)bh * 64 + w * 16 + l15) * 2880;
  f32x4 zz = {0.f, 0.f, 0.f, 0.f};
  f32x4 accO = zz;

  // ---- scores (stored as exp, truncated): wave w keys [w*144, w*144+144) ----
  __builtin_amdgcn_s_setprio(1);
  #pragma unroll 3
  for (int t = 0; t < 9; ++t) {
    const int wk = w * 144 + t * 16;
    const u16* kr = kp + (size_t)(c * 576 + wk + l15) * 64 + ko;
    s16x8 kf0 = *(const s16x8*)&kr[0];
    s16x8 kf1 = *(const s16x8*)&kr[32];
    f32x4 a0 = zz;
    a0 = MFMA_B16(aQ[0], kf0, a0);
    a0 = MFMA_B16(aQ[1], kf1, a0);
    #pragma unroll
    for (int r = 0; r < 4; ++r)
      s_p[(rg * 4 + r) * PST + wk + l15] =
          (u16)(__float_as_uint(__expf(a0[r])) >> 16);   // truncate
  }
  __builtin_amdgcn_s_setprio(0);
  __syncthreads();

  if (c == 0) {
    // ---- denom over qa: wave w owns rows w*4..w*4+3 (vectorized reads) ----
    #pragma unroll
    for (int ri = 0; ri < 4; ++ri) {
      const int q = w * 4 + ri;
      const u32* rp = (const u32*)&s_p[q * PST];
      uint4 dv = *(const uint4*)&rp[lane * 4];   // u16 idx 8L..8L+7
      const u16 tl = s_p[q * PST + 512 + lane];  // u16 idx 512+L (last 64 real keys)
      float s = sumpair(dv.x) + sumpair(dv.y) + sumpair(dv.z) + sumpair(dv.w)
              + bf2f(tl);
      #pragma unroll
      for (int off = 1; off < 64; off <<= 1) s += __shfl_xor(s, off);
      if (lane == 0) dpart[(size_t)(bq * 5 + c) * 16 + q] = s;
    }
    // no second barrier: PV and denom both only READ s_p
  } else {
    // ---- top-32, 2-row interleaved, 9 keys/lane, 10-bit compact keys ----
    #pragma unroll
    for (int rp2 = 0; rp2 < 2; ++rp2) {
      const int qA = w * 4 + rp2 * 2, qB = qA + 1;
      u32* rpA = (u32*)&s_p[qA * PST];
      u32* rpB = (u32*)&s_p[qB * PST];
      unsigned kA[9], kB[9];
      {
        uint4 dA = *(const uint4*)&rpA[lane * 4];
        uint4 dB = *(const uint4*)&rpB[lane * 4];
        kA[0]=dA.x&0xFFFF; kA[1]=dA.x>>16; kA[2]=dA.y&0xFFFF; kA[3]=dA.y>>16;
        kA[4]=dA.z&0xFFFF; kA[5]=dA.z>>16; kA[6]=dA.w&0xFFFF; kA[7]=dA.w>>16;
        kA[8]=s_p[qA * PST + 512 + lane];
        kB[0]=dB.x&0xFFFF; kB[1]=dB.x>>16; kB[2]=dB.y&0xFFFF; kB[3]=dB.y>>16;
        kB[4]=dB.z&0xFFFF; kB[5]=dB.z>>16; kB[6]=dB.w&0xFFFF; kB[7]=dB.w>>16;
        kB[8]=s_p[qB * PST + 512 + lane];
      }
      #pragma unroll
      for (int j = 0; j < 9; ++j) {              // compact: clamp(k-BIAS, 0, 1023)
        int tA2 = (int)kA[j] - BIAS;
        int tB2 = (int)kB[j] - BIAS;
        kA[j] = (unsigned)(tA2 < 0 ? 0 : (tA2 > 1023 ? 1023 : tA2));
        kB[j] = (unsigned)(tB2 < 0 ? 0 : (tB2 > 1023 ? 1023 : tB2));
      }
      unsigned pfA = 0, pfB = 0;
      int cgA = 0, cgB = 0;                      // cnt(>= pf_final), exact
      #pragma unroll
      for (int bit = 9; bit >= 0; --bit) {
        const unsigned cA = pfA | (1u << bit), cB = pfB | (1u << bit);
        int nA = 0, nB = 0;
        #pragma unroll
        for (int j = 0; j < 9; ++j) {
          nA += __popcll(__ballot(kA[j] >= cA));
          nB += __popcll(__ballot(kB[j] >= cB));
        }
        if (nA >= 32) { pfA = cA; cgA = nA; }
        if (nB >= 32) { pfB = cB; cgB = nB; }
      }
      // ---- writeback per row: selected keep exp, others -> 0 (packed) ----
      #pragma unroll
      for (int rr = 0; rr < 2; ++rr) {
        const unsigned* k = rr ? kB : kA;
        const unsigned pf = rr ? pfB : pfA;
        const int cg = rr ? cgB : cgA;
        u32* rp = rr ? rpB : rpA;
        const int q = rr ? qB : qA;
        u32 wd[4];
        u32 w9;
        float dsum = 0.f;
        if (cg == 32 && pf != 0u) {
          // ---- fast path: no boundary tie -> sel is pure per-lane VALU ----
          #pragma unroll
          for (int j2 = 0; j2 < 4; ++j2) {
            const u32 lo16 = (k[j2 * 2]     >= pf) ? (k[j2 * 2]     + (u32)BIAS) : 0u;
            const u32 hi16 = (k[j2 * 2 + 1] >= pf) ? (k[j2 * 2 + 1] + (u32)BIAS) : 0u;
            const u32 packed = lo16 | (hi16 << 16);
            wd[j2] = packed;
            dsum += sumpair(packed);
          }
          w9 = (k[8] >= pf) ? (k[8] + (u32)BIAS) : 0u;
          dsum += __uint_as_float(w9 << 16);
        } else {
          // ---- tie path: exact scan-order tie break via ballots ----
          int cnt_gt = 0;
          #pragma unroll
          for (int j = 0; j < 9; ++j)
            cnt_gt += __popcll(__ballot(k[j] > pf));
          const int rem = 32 - cnt_gt;
          int run_eq = 0;
          #pragma unroll
          for (int j2 = 0; j2 < 4; ++j2) {
            u32 packed = 0;
            #pragma unroll
            for (int h2 = 0; h2 < 2; ++h2) {
              const int j = j2 * 2 + h2;
              const unsigned kj = k[j];
              unsigned long long eq = __ballot(kj == pf);
              const bool sel = (kj > pf) ||
                  (kj == pf && run_eq + lanes_below(eq) < rem);
              run_eq += __popcll(eq);
              const u32 w16 = sel ? (kj + (u32)BIAS) : 0u;
              packed |= w16 << (16 * h2);
            }
            wd[j2] = packed;
            dsum += sumpair(packed);
          }
          {
            const unsigned kj = k[8];
            unsigned long long eq = __ballot(kj == pf);
            const bool sel = (kj > pf) ||
                (kj == pf && run_eq + lanes_below(eq) < rem);
            w9 = sel ? (kj + (u32)BIAS) : 0u;
            dsum += __uint_as_float(w9 << 16);
          }
        }
        *(uint4*)&rp[lane * 4] = *(const uint4*)&wd[0];
        s_p[q * PST + 512 + lane] = (u16)w9;
        #pragma unroll
        for (int off = 1; off < 64; off <<= 1) dsum += __shfl_xor(dsum, off);
        if (lane == 0) dpart[(size_t)(bq * 5 + c) * 16 + q] = dsum;
      }
    }
    __syncthreads();   // P writeback visible before PV reads all rows
  }

  // ---- dense PV over this chunk: wave w owns output cols d = w*16..+15 ----
  __builtin_amdgcn_s_setprio(1);
  #pragma unroll 3
  for (int k0 = 0; k0 < 576; k0 += 32) {
    s16x8 vf = *(const s16x8*)&vt[(size_t)c * 576 + k0 + ko];
    s16x8 pa = *(const s16x8*)&s_p[l15 * PST + k0 + ko];
    accO = MFMA_B16(pa, vf, accO);
  }
  __builtin_amdgcn_s_setprio(0);

  // ---- write O partial (bf16, no division) ----
  u16* op = opart + (size_t)(bq * 5 + c) * 1024;
  const int d = w * 16 + l15;
  #pragma unroll
  for (int r = 0; r < 4; ++r) {
    const int row = rg * 4 + r;
    op[row * 64 + d] = f2bf(accO[r]);
  }
}

// ---------------- attn reduce: sum 5 chunk partials, divide, -> aout bf16 ----------------
__global__ __launch_bounds__(256) void attn_reduce(
    const u16* __restrict__ opart, const float* __restrict__ dpart,
    u16* __restrict__ aout)
{
  const int bq = blockIdx.x;                 // (b*12+h)*36+qt
  const int t = threadIdx.x;
  const int b = bq / 432;
  const int h = (bq / 36) % 12;
  const int qt = bq % 36;
  const u16* ob = opart + (size_t)bq * 5 * 1024;
  const float* db = dpart + (size_t)bq * 5 * 16;
  const int e = t * 4;
  const int row = e >> 6, d0 = e & 63;
  float dn = 0.f;
  #pragma unroll
  for (int c = 0; c < 5; ++c) dn += db[c * 16 + row];
  float o0 = 0.f, o1 = 0.f, o2 = 0.f, o3 = 0.f;
  #pragma unroll
  for (int c = 0; c < 5; ++c) {
    uint2 v = *(const uint2*)&ob[c * 1024 + e];
    o0 += bf2f((u16)(v.x & 0xFFFF)); o1 += bf2f((u16)(v.x >> 16));
    o2 += bf2f((u16)(v.y & 0xFFFF)); o3 += bf2f((u16)(v.y >> 16));
  }
  const float inv = 1.f / dn;
  uint2 ov;
  ov.x = (u32)f2bf(o0 * inv) | ((u32)f2bf(o1 * inv) << 16);
  ov.y = (u32)f2bf(o2 * inv) | ((u32)f2bf(o3 * inv) << 16);
  *(uint2*)&aout[((size_t)(b * 576 + qt * 16 + row)) * 768 + h * 64 + d0] = ov;
}

// ---------------- host launcher ----------------
extern "C" void kernel_launch(void* const* d_in, const int* in_sizes, int n_in,
                              void* d_out, int out_size, void* d_ws, size_t ws_size,
                              hipStream_t stream)
{
  const float* x      = (const float*)d_in[0];
  const float* qkv_w  = (const float*)d_in[1];
  const float* proj_w = (const float*)d_in[2];
  const float* proj_b = (const float*)d_in[3];
  float* out = (float*)d_out;

  char* ws = (char*)d_ws;
  size_t off = 0;
  auto alloc = [&](size_t bytes) -> void* {
    void* p = ws + off;
    off += (bytes + 255) & ~(size_t)255;
    return p;
  };
  u16* xb    = (u16*)alloc((size_t)23040 * 768 * 2);    // x bf16
  u16* wqb   = (u16*)alloc((size_t)2304 * 768 * 2);     // qkv_w bf16
  u16* wpb   = (u16*)alloc((size_t)768 * 768 * 2);      // proj_w bf16
  u16* qbuf  = (u16*)alloc((size_t)96 * 576 * 64 * 2);  // q (pre-scaled 1/8)
  u16* kbuf  = (u16*)alloc((size_t)96 * 2880 * 64 * 2); // k
  u16* vtb   = (u16*)alloc((size_t)96 * 64 * 2880 * 2); // v^T, full 2880 keys
  u16* aout  = (u16*)alloc((size_t)4608 * 768 * 2);     // attention output (B*hw, C)
  u16* opart = (u16*)alloc((size_t)17280 * 1024 * 2);   // per-chunk O partials (bf16)
  float* dpart = (float*)alloc((size_t)17280 * 16 * 4); // per-chunk denom partials

  cvt_x_tail<<<17280, 256, 0, stream>>>(x, xb, out);    // x read once: xb + tail copy
  cvt_kernel<<<1728, 256, 0, stream>>>(qkv_w, wqb, 1769472 / 4);
  cvt_kernel<<<576, 256, 0, stream>>>(proj_w, wpb, 589824 / 4);
  gemm_nt<0><<<3240, 256, 0, stream>>>(xb, wqb, nullptr,
                                       qbuf, kbuf, vtb, nullptr);
  attn_kernel<<<17280, 256, 0, stream>>>(qbuf, kbuf, vtb, opart, dpart);
  attn_reduce<<<3456, 256, 0, stream>>>(opart, dpart, aout);
  gemm_nt<1><<<216, 256, 0, stream>>>(aout, wpb, proj_b,
                                      nullptr, nullptr, nullptr, out);
}

// Round 17
// 463.537 us; speedup vs baseline: 1.1383x; 1.0017x over previous
//
#include <hip/hip_runtime.h>
#include <hip/hip_bf16.h>

// Attention_89335319756981 — MI355X bf16-MFMA implementation, round 17 (final consolidation).
// B=8, N=2880 (hw=576 + T=4 frames of 576), C=768, H=12, hd=64, TOPK=32.
//
// Round-17 (base = round 16, best: 464.3 us): risk-free deltas only.
//  - weight converts merged into one launch.
//  - attn setprio removed (measured null in r15).
//  - all else identical to round 16.

using s16x8 = __attribute__((ext_vector_type(8))) short;
using f32x4 = __attribute__((ext_vector_type(4))) float;
typedef unsigned short u16;
typedef unsigned int u32;

#define MFMA_B16(A,B,C) __builtin_amdgcn_mfma_f32_16x16x32_bf16(A,B,C,0,0,0)

__device__ __forceinline__ u16 f2bf(float f) {
  unsigned u = __float_as_uint(f);
  u += 0x7FFFu + ((u >> 16) & 1u);          // RNE, no NaN inputs here
  return (u16)(u >> 16);
}
__device__ __forceinline__ float bf2f(u16 h) {
  return __uint_as_float(((unsigned)h) << 16);
}
__device__ __forceinline__ int lanes_below(unsigned long long m) {
  return __builtin_amdgcn_mbcnt_hi((unsigned)(m >> 32),
         __builtin_amdgcn_mbcnt_lo((unsigned)m, 0));
}
__device__ __forceinline__ void stage16(const u16* __restrict__ g, u16* l) {
  __builtin_amdgcn_global_load_lds(
      (const __attribute__((address_space(1))) unsigned int*)g,
      (__attribute__((address_space(3))) unsigned int*)l, 16, 0, 0);
}
// sum of the two bf16 halves of a packed dword (zeros contribute 0)
__device__ __forceinline__ float sumpair(u32 d) {
  return __uint_as_float(d << 16) + __uint_as_float(d & 0xFFFF0000u);
}

// ---------------- fused: x -> bf16 (all rows) + tail passthrough copy ----------------
__global__ __launch_bounds__(256) void cvt_x_tail(const float* __restrict__ x,
                                                  u16* __restrict__ xb,
                                                  float* __restrict__ out) {
  const int i = blockIdx.x * blockDim.x + threadIdx.x;  // float4 units, 4423680 total
  float4 v = ((const float4*)x)[i];
  unsigned lo = (unsigned)f2bf(v.x) | ((unsigned)f2bf(v.y) << 16);
  unsigned hi = (unsigned)f2bf(v.z) | ((unsigned)f2bf(v.w) << 16);
  uint2 o; o.x = lo; o.y = hi;
  ((uint2*)xb)[i] = o;
  const int b = i / 552960;                 // 2880*768/4 per batch
  const int off = i - b * 552960;
  if (off >= 110592)                        // rows >= 576: exact f32 passthrough
    ((float4*)out)[i] = v;
}

// ---------------- f32 -> bf16 convert, both weights in one launch ----------------
// [0, 442368) float4 units -> qkv_w/wqb; [442368, 589824) -> proj_w/wpb.
__global__ __launch_bounds__(256) void cvt_weights(const float* __restrict__ qkv_w,
                                                   const float* __restrict__ proj_w,
                                                   u16* __restrict__ wqb,
                                                   u16* __restrict__ wpb) {
  const int i = blockIdx.x * blockDim.x + threadIdx.x;  // 0 .. 589823
  const bool isq = (i < 442368);
  const int j = isq ? i : (i - 442368);
  const float4 v = isq ? ((const float4*)qkv_w)[j] : ((const float4*)proj_w)[j];
  unsigned lo = (unsigned)f2bf(v.x) | ((unsigned)f2bf(v.y) << 16);
  unsigned hi = (unsigned)f2bf(v.z) | ((unsigned)f2bf(v.w) << 16);
  uint2 o; o.x = lo; o.y = hi;
  if (isq) ((uint2*)wqb)[j] = o;
  else     ((uint2*)wpb)[j] = o;
}

// ---------------- NT GEMM, 128x128 tile, BK=64, global_load_lds ----------------
// 1D grid, bijective XCD swizzle: L = (bid%8)*(nwg/8) + bid/8.
template<int MODE>
__global__ __launch_bounds__(256) void gemm_nt(
    const u16* __restrict__ A, const u16* __restrict__ Bw,
    const float* __restrict__ bias,
    u16* __restrict__ qbuf, u16* __restrict__ kbuf,
    u16* __restrict__ vtb, float* __restrict__ fout)
{
  __shared__ __align__(16) u16 smem[128 * 128];   // 32KB: sA|sB, reused for vT
  u16* sA = smem;
  u16* sB = smem + 128 * 64;
  constexpr int NX = (MODE == 0) ? 18 : 6;
  constexpr int QX = (MODE == 0) ? 405 : 27;      // nwg / 8 (exact)
  const int bid = blockIdx.x;
  const int Lw = (bid & 7) * QX + (bid >> 3);     // bijective XCD remap
  const int n0 = (Lw % NX) * 128;
  const int m0 = (Lw / NX) * 128;
  if (MODE == 0 && n0 < 768) {
    const int s = m0 % 2880;
    if (s >= 576 && s + 128 <= 2880) return;
  }
  const int tid = threadIdx.x;
  const int w = tid >> 6, lane = tid & 63;
  const int l15 = lane & 15, rg = lane >> 4;
  const int ko = rg * 8;
  const int mq = (w >> 1) * 64, nq = (w & 1) * 64;
  const int trow = tid >> 3, tcol = (tid & 7) * 8;

  f32x4 z = {0.f, 0.f, 0.f, 0.f};
  f32x4 acc[4][4];
  #pragma unroll
  for (int i = 0; i < 4; ++i)
    #pragma unroll
    for (int j = 0; j < 4; ++j) acc[i][j] = z;

  for (int k0 = 0; k0 < 768; k0 += 64) {
    __syncthreads();
    #pragma unroll
    for (int i = 0; i < 4; ++i) {
      stage16(&A[(size_t)(m0 + trow + i * 32) * 768 + k0 + tcol],
              &sA[(trow + i * 32) * 64 + tcol]);
      stage16(&Bw[(size_t)(n0 + trow + i * 32) * 768 + k0 + tcol],
              &sB[(trow + i * 32) * 64 + tcol]);
    }
    __syncthreads();
    #pragma unroll
    for (int kk = 0; kk < 2; ++kk) {
      const int ko2 = kk * 32 + ko;
      s16x8 af[4], bf[4];
      #pragma unroll
      for (int i = 0; i < 4; ++i) {
        af[i] = *(const s16x8*)&sA[(mq + i * 16 + l15) * 64 + ko2];
        bf[i] = *(const s16x8*)&sB[(nq + i * 16 + l15) * 64 + ko2];
      }
      #pragma unroll
      for (int mi = 0; mi < 4; ++mi)
        #pragma unroll
        for (int ni = 0; ni < 4; ++ni)
          acc[mi][ni] = MFMA_B16(af[mi], bf[ni], acc[mi][ni]);
    }
  }

  if (MODE == 0) {
    const int which = n0 / 768;
    const int nb = n0 % 768;
    if (which == 2) {
      __syncthreads();
      #pragma unroll
      for (int mi = 0; mi < 4; ++mi)
        #pragma unroll
        for (int ni = 0; ni < 4; ++ni)
          #pragma unroll
          for (int r = 0; r < 4; ++r)
            smem[(mq + mi * 16 + rg * 4 + r) * 128 + nq + ni * 16 + l15] =
                f2bf(acc[mi][ni][r]);
      __syncthreads();
      const int c = tid & 127, kh = tid >> 7;
      const int gm0 = m0 + kh * 64;
      const int bb = gm0 / 2880, rr0 = gm0 - bb * 2880;
      const int ng = nb + c;
      const int hh = ng >> 6, dd = ng & 63;
      u16* dst = vtb + ((size_t)((bb * 12 + hh) * 64 + dd)) * 2880 + rr0;
      #pragma unroll
      for (int seg = 0; seg < 4; ++seg) {
        u16 tmp[16];
        #pragma unroll
        for (int i = 0; i < 16; ++i)
          tmp[i] = smem[(kh * 64 + seg * 16 + i) * 128 + c];
        *(int4*)&dst[seg * 16]     = *(const int4*)&tmp[0];
        *(int4*)&dst[seg * 16 + 8] = *(const int4*)&tmp[8];
      }
    } else {
      #pragma unroll
      for (int mi = 0; mi < 4; ++mi)
        #pragma unroll
        for (int ni = 0; ni < 4; ++ni)
          #pragma unroll
          for (int r = 0; r < 4; ++r) {
            const int gm = m0 + mq + mi * 16 + rg * 4 + r;
            const int b  = gm / 2880;
            const int rr = gm - b * 2880;
            const int ng = nb + nq + ni * 16 + l15;
            const int h  = ng >> 6, d = ng & 63;
            const float cc = acc[mi][ni][r];
            if (which == 0) {
              if (rr < 576)
                qbuf[((size_t)(b * 12 + h) * 576 + rr) * 64 + d] = f2bf(cc * 0.125f);
            } else {
              kbuf[((size_t)(b * 12 + h) * 2880 + rr) * 64 + d] = f2bf(cc);
            }
          }
    }
  } else {
    #pragma unroll
    for (int mi = 0; mi < 4; ++mi)
      #pragma unroll
      for (int ni = 0; ni < 4; ++ni)
        #pragma unroll
        for (int r = 0; r < 4; ++r) {
          const int gm = m0 + mq + mi * 16 + rg * 4 + r;
          const int gn = n0 + nq + ni * 16 + l15;
          const int b = gm / 576;
          const int q = gm - b * 576;
          fout[((size_t)b * 2880 + q) * 768 + gn] = acc[mi][ni][r] + bias[gn];
        }
  }
}

// ---------------- fused attention, round 17: one key-chunk per block ----------------
// block = (b, h, 16 q-rows, chunk c), 256 threads (4 waves), ~20.7KB LDS,
// 7 blocks/CU. Scores stored as exp (trunc bf16). Top-32: 10-round ballot
// binary search on 10-bit compact keys (9 keys/lane), 2-row interleaved;
// writeback: ballot-free fast path when no boundary tie, exact tie path kept.
// Partials: O_c bf16, denom_c f32 -> ws.
__global__ __launch_bounds__(256, 7) void attn_kernel(
    const u16* __restrict__ qbuf, const u16* __restrict__ kbuf,
    const u16* __restrict__ vtb,
    u16* __restrict__ opart, float* __restrict__ dpart)
{
  constexpr int PST = 648;                       // u16 stride: 1296B
  constexpr int BIAS = 0x3E80;                   // exp-bf16 code of ~0.25
  __shared__ __align__(16) u16 s_p[16 * PST];    // 20.7 KB exp(scores) / P

  const int bid = blockIdx.x;
  const int L = (bid & 7) * 2160 + (bid >> 3);   // 17280 = 8 XCD * 2160
  const int b   = L / 2160;
  const int rm  = L % 2160;
  const int c   = rm / 432;                      // chunk 0..4
  const int h   = (rm / 36) % 12;
  const int qt  = rm % 36;
  const int bh = b * 12 + h;
  const int q0 = qt * 16;
  const int bq = bh * 36 + qt;
  const int tid = threadIdx.x, w = tid >> 6, lane = tid & 63;
  const int l15 = lane & 15, rg = lane >> 4;
  const int ko = rg * 8;

  // Q A-fragments for the block's 16 rows (2 K-halves)
  const u16* qp = qbuf + ((size_t)bh * 576 + q0) * 64;
  s16x8 aQ[2];
  aQ[0] = *(const s16x8*)&qp[l15 * 64 + ko];
  aQ[1] = *(const s16x8*)&qp[l15 * 64 + 32 + ko];

  const u16* kp = kbuf + (size_t)bh * 2880 * 64;
  const u16* vt = vtb + ((size_t)bh * 64 + w * 16 + l15) * 2880;
  f32x4 zz = {0.f, 0.f, 0.f, 0.f};
  f32x4 accO = zz;

  // ---- scores (stored as exp, truncated): wave w keys [w*144, w*144+144) ----
  #pragma unroll 3
  for (int t = 0; t < 9; ++t) {
    const int wk = w * 144 + t * 16;
    const u16* kr = kp + (size_t)(c * 576 + wk + l15) * 64 + ko;
    s16x8 kf0 = *(const s16x8*)&kr[0];
    s16x8 kf1 = *(const s16x8*)&kr[32];
    f32x4 a0 = zz;
    a0 = MFMA_B16(aQ[0], kf0, a0);
    a0 = MFMA_B16(aQ[1], kf1, a0);
    #pragma unroll
    for (int r = 0; r < 4; ++r)
      s_p[(rg * 4 + r) * PST + wk + l15] =
          (u16)(__float_as_uint(__expf(a0[r])) >> 16);   // truncate
  }
  __syncthreads();

  if (c == 0) {
    // ---- denom over qa: wave w owns rows w*4..w*4+3 (vectorized reads) ----
    #pragma unroll
    for (int ri = 0; ri < 4; ++ri) {
      const int q = w * 4 + ri;
      const u32* rp = (const u32*)&s_p[q * PST];
      uint4 dv = *(const uint4*)&rp[lane * 4];   // u16 idx 8L..8L+7
      const u16 tl = s_p[q * PST + 512 + lane];  // u16 idx 512+L (last 64 real keys)
      float s = sumpair(dv.x) + sumpair(dv.y) + sumpair(dv.z) + sumpair(dv.w)
              + bf2f(tl);
      #pragma unroll
      for (int off = 1; off < 64; off <<= 1) s += __shfl_xor(s, off);
      if (lane == 0) dpart[(size_t)(bq * 5 + c) * 16 + q] = s;
    }
    // no second barrier: PV and denom both only READ s_p
  } else {
    // ---- top-32, 2-row interleaved, 9 keys/lane, 10-bit compact keys ----
    #pragma unroll
    for (int rp2 = 0; rp2 < 2; ++rp2) {
      const int qA = w * 4 + rp2 * 2, qB = qA + 1;
      u32* rpA = (u32*)&s_p[qA * PST];
      u32* rpB = (u32*)&s_p[qB * PST];
      unsigned kA[9], kB[9];
      {
        uint4 dA = *(const uint4*)&rpA[lane * 4];
        uint4 dB = *(const uint4*)&rpB[lane * 4];
        kA[0]=dA.x&0xFFFF; kA[1]=dA.x>>16; kA[2]=dA.y&0xFFFF; kA[3]=dA.y>>16;
        kA[4]=dA.z&0xFFFF; kA[5]=dA.z>>16; kA[6]=dA.w&0xFFFF; kA[7]=dA.w>>16;
        kA[8]=s_p[qA * PST + 512 + lane];
        kB[0]=dB.x&0xFFFF; kB[1]=dB.x>>16; kB[2]=dB.y&0xFFFF; kB[3]=dB.y>>16;
        kB[4]=dB.z&0xFFFF; kB[5]=dB.z>>16; kB[6]=dB.w&0xFFFF; kB[7]=dB.w>>16;
        kB[8]=s_p[qB * PST + 512 + lane];
      }
      #pragma unroll
      for (int j = 0; j < 9; ++j) {              // compact: clamp(k-BIAS, 0, 1023)
        int tA2 = (int)kA[j] - BIAS;
        int tB2 = (int)kB[j] - BIAS;
        kA[j] = (unsigned)(tA2 < 0 ? 0 : (tA2 > 1023 ? 1023 : tA2));
        kB[j] = (unsigned)(tB2 < 0 ? 0 : (tB2 > 1023 ? 1023 : tB2));
      }
      unsigned pfA = 0, pfB = 0;
      int cgA = 0, cgB = 0;                      // cnt(>= pf_final), exact
      #pragma unroll
      for (int bit = 9; bit >= 0; --bit) {
        const unsigned cA = pfA | (1u << bit), cB = pfB | (1u << bit);
        int nA = 0, nB = 0;
        #pragma unroll
        for (int j = 0; j < 9; ++j) {
          nA += __popcll(__ballot(kA[j] >= cA));
          nB += __popcll(__ballot(kB[j] >= cB));
        }
        if (nA >= 32) { pfA = cA; cgA = nA; }
        if (nB >= 32) { pfB = cB; cgB = nB; }
      }
      // ---- writeback per row: selected keep exp, others -> 0 (packed) ----
      #pragma unroll
      for (int rr = 0; rr < 2; ++rr) {
        const unsigned* k = rr ? kB : kA;
        const unsigned pf = rr ? pfB : pfA;
        const int cg = rr ? cgB : cgA;
        u32* rp = rr ? rpB : rpA;
        const int q = rr ? qB : qA;
        u32 wd[4];
        u32 w9;
        float dsum = 0.f;
        if (cg == 32 && pf != 0u) {
          // ---- fast path: no boundary tie -> sel is pure per-lane VALU ----
          #pragma unroll
          for (int j2 = 0; j2 < 4; ++j2) {
            const u32 lo16 = (k[j2 * 2]     >= pf) ? (k[j2 * 2]     + (u32)BIAS) : 0u;
            const u32 hi16 = (k[j2 * 2 + 1] >= pf) ? (k[j2 * 2 + 1] + (u32)BIAS) : 0u;
            const u32 packed = lo16 | (hi16 << 16);
            wd[j2] = packed;
            dsum += sumpair(packed);
          }
          w9 = (k[8] >= pf) ? (k[8] + (u32)BIAS) : 0u;
          dsum += __uint_as_float(w9 << 16);
        } else {
          // ---- tie path: exact scan-order tie break via ballots ----
          int cnt_gt = 0;
          #pragma unroll
          for (int j = 0; j < 9; ++j)
            cnt_gt += __popcll(__ballot(k[j] > pf));
          const int rem = 32 - cnt_gt;
          int run_eq = 0;
          #pragma unroll
          for (int j2 = 0; j2 < 4; ++j2) {
            u32 packed = 0;
            #pragma unroll
            for (int h2 = 0; h2 < 2; ++h2) {
              const int j = j2 * 2 + h2;
              const unsigned kj = k[j];
              unsigned long long eq = __ballot(kj == pf);
              const bool sel = (kj > pf) ||
                  (kj == pf && run_eq + lanes_below(eq) < rem);
              run_eq += __popcll(eq);
              const u32 w16 = sel ? (kj + (u32)BIAS) : 0u;
              packed |= w16 << (16 * h2);
            }
            wd[j2] = packed;
            dsum += sumpair(packed);
          }
          {
            const unsigned kj = k[8];
            unsigned long long eq = __ballot(kj == pf);
            const bool sel = (kj > pf) ||
                (kj == pf && run_eq + lanes_below(eq) < rem);
            w9 = sel ? (kj + (u32)BIAS) : 0u;
            dsum += __uint_as_float(w9 << 16);
          }
        }
        *(uint4*)&rp[lane * 4] = *(const uint4*)&wd[0];
        s_p[q * PST + 512 + lane] = (u16)w9;
        #pragma unroll
        for (int off = 1; off < 64; off <<= 1) dsum += __shfl_xor(dsum, off);
        if (lane == 0) dpart[(size_t)(bq * 5 + c) * 16 + q] = dsum;
      }
    }
    __syncthreads();   // P writeback visible before PV reads all rows
  }

  // ---- dense PV over this chunk: wave w owns output cols d = w*16..+15 ----
  #pragma unroll 3
  for (int k0 = 0; k0 < 576; k0 += 32) {
    s16x8 vf = *(const s16x8*)&vt[(size_t)c * 576 + k0 + ko];
    s16x8 pa = *(const s16x8*)&s_p[l15 * PST + k0 + ko];
    accO = MFMA_B16(pa, vf, accO);
  }

  // ---- write O partial (bf16, no division) ----
  u16* op = opart + (size_t)(bq * 5 + c) * 1024;
  const int d = w * 16 + l15;
  #pragma unroll
  for (int r = 0; r < 4; ++r) {
    const int row = rg * 4 + r;
    op[row * 64 + d] = f2bf(accO[r]);
  }
}

// ---------------- attn reduce: sum 5 chunk partials, divide, -> aout bf16 ----------------
__global__ __launch_bounds__(256) void attn_reduce(
    const u16* __restrict__ opart, const float* __restrict__ dpart,
    u16* __restrict__ aout)
{
  const int bq = blockIdx.x;                 // (b*12+h)*36+qt
  const int t = threadIdx.x;
  const int b = bq / 432;
  const int h = (bq / 36) % 12;
  const int qt = bq % 36;
  const u16* ob = opart + (size_t)bq * 5 * 1024;
  const float* db = dpart + (size_t)bq * 5 * 16;
  const int e = t * 4;
  const int row = e >> 6, d0 = e & 63;
  float dn = 0.f;
  #pragma unroll
  for (int c = 0; c < 5; ++c) dn += db[c * 16 + row];
  float o0 = 0.f, o1 = 0.f, o2 = 0.f, o3 = 0.f;
  #pragma unroll
  for (int c = 0; c < 5; ++c) {
    uint2 v = *(const uint2*)&ob[c * 1024 + e];
    o0 += bf2f((u16)(v.x & 0xFFFF)); o1 += bf2f((u16)(v.x >> 16));
    o2 += bf2f((u16)(v.y & 0xFFFF)); o3 += bf2f((u16)(v.y >> 16));
  }
  const float inv = 1.f / dn;
  uint2 ov;
  ov.x = (u32)f2bf(o0 * inv) | ((u32)f2bf(o1 * inv) << 16);
  ov.y = (u32)f2bf(o2 * inv) | ((u32)f2bf(o3 * inv) << 16);
  *(uint2*)&aout[((size_t)(b * 576 + qt * 16 + row)) * 768 + h * 64 + d0] = ov;
}

// ---------------- host launcher ----------------
extern "C" void kernel_launch(void* const* d_in, const int* in_sizes, int n_in,
                              void* d_out, int out_size, void* d_ws, size_t ws_size,
                              hipStream_t stream)
{
  const float* x      = (const float*)d_in[0];
  const float* qkv_w  = (const float*)d_in[1];
  const float* proj_w = (const float*)d_in[2];
  const float* proj_b = (const float*)d_in[3];
  float* out = (float*)d_out;

  char* ws = (char*)d_ws;
  size_t off = 0;
  auto alloc = [&](size_t bytes) -> void* {
    void* p = ws + off;
    off += (bytes + 255) & ~(size_t)255;
    return p;
  };
  u16* xb    = (u16*)alloc((size_t)23040 * 768 * 2);    // x bf16
  u16* wqb   = (u16*)alloc((size_t)2304 * 768 * 2);     // qkv_w bf16
  u16* wpb   = (u16*)alloc((size_t)768 * 768 * 2);      // proj_w bf16
  u16* qbuf  = (u16*)alloc((size_t)96 * 576 * 64 * 2);  // q (pre-scaled 1/8)
  u16* kbuf  = (u16*)alloc((size_t)96 * 2880 * 64 * 2); // k
  u16* vtb   = (u16*)alloc((size_t)96 * 64 * 2880 * 2); // v^T, full 2880 keys
  u16* aout  = (u16*)alloc((size_t)4608 * 768 * 2);     // attention output (B*hw, C)
  u16* opart = (u16*)alloc((size_t)17280 * 1024 * 2);   // per-chunk O partials (bf16)
  float* dpart = (float*)alloc((size_t)17280 * 16 * 4); // per-chunk denom partials

  cvt_x_tail<<<17280, 256, 0, stream>>>(x, xb, out);    // x read once: xb + tail copy
  cvt_weights<<<2304, 256, 0, stream>>>(qkv_w, proj_w, wqb, wpb);
  gemm_nt<0><<<3240, 256, 0, stream>>>(xb, wqb, nullptr,
                                       qbuf, kbuf, vtb, nullptr);
  attn_kernel<<<17280, 256, 0, stream>>>(qbuf, kbuf, vtb, opart, dpart);
  attn_reduce<<<3456, 256, 0, stream>>>(opart, dpart, aout);
  gemm_nt<1><<<216, 256, 0, stream>>>(aout, wpb, proj_b,
                                      nullptr, nullptr, nullptr, out);
}